// Round 8
// baseline (432.310 us; speedup 1.0000x reference)
//
#include <hip/hip_runtime.h>
#include <math.h>

namespace {

constexpr int kB  = 2;
constexpr int kL  = 8192;
constexpr int kD  = 768;

typedef _Float16 f16;
typedef __attribute__((ext_vector_type(4))) _Float16 f16x4;
typedef __attribute__((ext_vector_type(8))) _Float16 f16x8;
typedef __attribute__((ext_vector_type(4))) float f32x4;

__device__ __forceinline__ void gload_lds16(const f16* g, f16* l) {
  __builtin_amdgcn_global_load_lds(
      (__attribute__((address_space(1))) void*)(g),
      (__attribute__((address_space(3))) void*)(l), 16, 0, 0);
}

// ---------------- K0: fp32 -> fp16 conversion ----------------
__global__ __launch_bounds__(256) void cvt_f32_f16(
    const float* __restrict__ s, f16* __restrict__ d, int n) {
  int t = blockIdx.x * 256 + threadIdx.x;
  int i = t * 8;
  if (i >= n) return;
  float4 a = *(const float4*)(s + i);
  float4 b = *(const float4*)(s + i + 4);
  f16x8 v;
  v[0] = (f16)a.x; v[1] = (f16)a.y; v[2] = (f16)a.z; v[3] = (f16)a.w;
  v[4] = (f16)b.x; v[5] = (f16)b.y; v[6] = (f16)b.z; v[7] = (f16)b.w;
  *(f16x8*)(d + i) = v;
}

// ---------------- K1: qkv projection (fp16 MFMA), split outputs ----------------
__global__ __launch_bounds__(256) void hgemm_qkv(
    const f16* __restrict__ A, const f16* __restrict__ W,
    f16* __restrict__ q16, f16* __restrict__ kv16, int M) {
  constexpr int K = 768;
  __shared__ f16 As[128 * 32];
  __shared__ f16 Bs[128 * 32];
  const int tid = threadIdx.x;
  const int bm = blockIdx.y, bn = blockIdx.x;
  const int lane = tid & 63;
  const int wv = tid >> 6;
  const int wr = wv >> 1, wc = wv & 1;
  const int fr = lane & 15, fq = lane >> 4;
  const int srow = tid >> 2;
  const int scol = (tid & 3) * 8;
  const f16* Ab = A + (size_t)bm * 128 * K;
  const f16* Wb = W + (size_t)bn * 128 * K;
  f32x4 acc[4][4];
#pragma unroll
  for (int m = 0; m < 4; ++m)
#pragma unroll
    for (int n = 0; n < 4; ++n)
#pragma unroll
      for (int j = 0; j < 4; ++j) acc[m][n][j] = 0.f;

  for (int k0 = 0; k0 < K; k0 += 32) {
#pragma unroll
    for (int i = 0; i < 2; ++i) {
      gload_lds16(Ab + (size_t)(i * 64 + srow) * K + k0 + scol, As + i * 2048 + wv * 512);
      gload_lds16(Wb + (size_t)(i * 64 + srow) * K + k0 + scol, Bs + i * 2048 + wv * 512);
    }
    __syncthreads();
    f16x8 af[4], bf[4];
#pragma unroll
    for (int m = 0; m < 4; ++m)
      af[m] = *(const f16x8*)&As[(wr * 64 + m * 16 + fr) * 32 + fq * 8];
#pragma unroll
    for (int n = 0; n < 4; ++n)
      bf[n] = *(const f16x8*)&Bs[(wc * 64 + n * 16 + fr) * 32 + fq * 8];
#pragma unroll
    for (int m = 0; m < 4; ++m)
#pragma unroll
      for (int n = 0; n < 4; ++n)
        acc[m][n] = __builtin_amdgcn_mfma_f32_16x16x32_f16(af[m], bf[n], acc[m][n], 0, 0, 0);
    __syncthreads();
  }
#pragma unroll
  for (int m = 0; m < 4; ++m) {
    int grow = bm * 128 + wr * 64 + m * 16 + fq * 4;
#pragma unroll
    for (int n = 0; n < 4; ++n) {
      int gcol = bn * 128 + wc * 64 + n * 16 + fr;
      f16* dst;
      int ldc, col;
      if (gcol < 768) { dst = q16; ldc = 768; col = gcol; }
      else            { dst = kv16; ldc = 1536; col = gcol - 768; }
#pragma unroll
      for (int j = 0; j < 4; ++j)
        dst[(size_t)(grow + j) * ldc + col] = (f16)acc[m][n][j];
    }
  }
}

// ---------------- K6: out = g16 @ w16out^T (fp16 MFMA, fp32 out) ----------------
__global__ __launch_bounds__(256) void hgemm_f32out(
    const f16* __restrict__ A, const f16* __restrict__ W,
    float* __restrict__ C, int M, int N) {
  constexpr int K = 768;
  __shared__ f16 As[128 * 32];
  __shared__ f16 Bs[128 * 32];
  const int tid = threadIdx.x;
  const int bm = blockIdx.y, bn = blockIdx.x;
  const int lane = tid & 63;
  const int wv = tid >> 6;
  const int wr = wv >> 1, wc = wv & 1;
  const int fr = lane & 15, fq = lane >> 4;
  const int srow = tid >> 2;
  const int scol = (tid & 3) * 8;
  const f16* Ab = A + (size_t)bm * 128 * K;
  const f16* Wb = W + (size_t)bn * 128 * K;
  f32x4 acc[4][4];
#pragma unroll
  for (int m = 0; m < 4; ++m)
#pragma unroll
    for (int n = 0; n < 4; ++n)
#pragma unroll
      for (int j = 0; j < 4; ++j) acc[m][n][j] = 0.f;

  for (int k0 = 0; k0 < K; k0 += 32) {
#pragma unroll
    for (int i = 0; i < 2; ++i) {
      gload_lds16(Ab + (size_t)(i * 64 + srow) * K + k0 + scol, As + i * 2048 + wv * 512);
      gload_lds16(Wb + (size_t)(i * 64 + srow) * K + k0 + scol, Bs + i * 2048 + wv * 512);
    }
    __syncthreads();
    f16x8 af[4], bf[4];
#pragma unroll
    for (int m = 0; m < 4; ++m)
      af[m] = *(const f16x8*)&As[(wr * 64 + m * 16 + fr) * 32 + fq * 8];
#pragma unroll
    for (int n = 0; n < 4; ++n)
      bf[n] = *(const f16x8*)&Bs[(wc * 64 + n * 16 + fr) * 32 + fq * 8];
#pragma unroll
    for (int m = 0; m < 4; ++m)
#pragma unroll
      for (int n = 0; n < 4; ++n)
        acc[m][n] = __builtin_amdgcn_mfma_f32_16x16x32_f16(af[m], bf[n], acc[m][n], 0, 0, 0);
    __syncthreads();
  }
#pragma unroll
  for (int m = 0; m < 4; ++m) {
    int grow = bm * 128 + wr * 64 + m * 16 + fq * 4;
#pragma unroll
    for (int n = 0; n < 4; ++n) {
      int gcol = bn * 128 + wc * 64 + n * 16 + fr;
#pragma unroll
      for (int j = 0; j < 4; ++j)
        C[(size_t)(grow + j) * N + gcol] = acc[m][n][j];
    }
  }
}

// ---------------- K2: depthwise causal conv(k=3) on k,v + product, transpose ----------------
__global__ __launch_bounds__(256) void dwconv_mul(
    const f16* __restrict__ kv,
    const float* __restrict__ sck_w, const float* __restrict__ sck_b,
    const float* __restrict__ scv_w, const float* __restrict__ scv_b,
    f16* __restrict__ u) {
  __shared__ float ks[34][33];
  __shared__ float vs[34][33];
  const int b  = blockIdx.z;
  const int d0 = blockIdx.y * 32;
  const int t0 = blockIdx.x * 32;
  const int tx = threadIdx.x;
  const int ty = threadIdx.y;
  const f16* base = kv + (size_t)b * kL * (2 * kD);
  for (int r = ty; r < 34; r += 8) {
    int t = t0 - 2 + r;
    float kk = 0.f, vv = 0.f;
    if (t >= 0) {
      kk = (float)base[(size_t)t * (2 * kD) + d0 + tx];
      vv = (float)base[(size_t)t * (2 * kD) + kD + d0 + tx];
    }
    ks[r][tx] = kk;
    vs[r][tx] = vv;
  }
  __syncthreads();
#pragma unroll
  for (int i = 0; i < 4; ++i) {
    int dd = ty + 8 * i;
    int d = d0 + dd;
    float kw0 = sck_w[d * 3 + 0], kw1 = sck_w[d * 3 + 1], kw2 = sck_w[d * 3 + 2];
    float vw0 = scv_w[d * 3 + 0], vw1 = scv_w[d * 3 + 1], vw2 = scv_w[d * 3 + 2];
    float kc = kw0 * ks[tx][dd] + kw1 * ks[tx + 1][dd] + kw2 * ks[tx + 2][dd] + sck_b[d];
    float vc = vw0 * vs[tx][dd] + vw1 * vs[tx + 1][dd] + vw2 * vs[tx + 2][dd] + scv_b[d];
    u[((size_t)b * kD + d) * kL + t0 + tx] = (f16)(kc * vc);
  }
}

// ---------------- K3: hyena filter  hfd[d][t] (fp32) ----------------
__global__ __launch_bounds__(256) void hyena_filter(
    const float* __restrict__ w1, const float* __restrict__ b1,
    const float* __restrict__ w2, const float* __restrict__ b2,
    const float* __restrict__ w3, const float* __restrict__ b3,
    const float* __restrict__ log_decay, float* __restrict__ hfd) {
  __shared__ float w1s[64 * 65];
  __shared__ float w2s[64 * 65];
  __shared__ float h2s[32][64];
  __shared__ float pe[64];
  __shared__ float h1v[64];
  const int tid = threadIdx.x;
  for (int i = tid; i < 64 * 64; i += 256) {
    w1s[(i >> 6) * 65 + (i & 63)] = w1[i];
    w2s[(i >> 6) * 65 + (i & 63)] = w2[i];
  }
  __syncthreads();
  const int tbase = blockIdx.x * 32;
  const float TWO_PI = 6.28318530717958647692f;
  for (int tt = 0; tt < 32; ++tt) {
    int t = tbase + tt;
    float tn = (float)t / 8191.0f;
    if (tid < 64) {
      float f = TWO_PI * (float)((tid & 31) + 1);
      pe[tid] = (tid < 32) ? sinf(tn * f) : cosf(tn * f);
    }
    __syncthreads();
    if (tid < 64) {
      float s = b1[tid];
      for (int j = 0; j < 64; ++j) s += pe[j] * w1s[tid * 65 + j];
      h1v[tid] = s / (1.0f + expf(-s));
    }
    __syncthreads();
    if (tid < 64) {
      float s = b2[tid];
      for (int j = 0; j < 64; ++j) s += h1v[j] * w2s[tid * 65 + j];
      h2s[tt][tid] = s / (1.0f + expf(-s));
    }
    __syncthreads();
  }
  for (int d = tid; d < kD; d += 256) {
    float a = fabsf(log_decay[d]);
    float bb = b3[d];
    float acc[32];
#pragma unroll
    for (int tt = 0; tt < 32; ++tt) acc[tt] = bb;
    for (int j = 0; j < 64; ++j) {
      float w = w3[d * 64 + j];
#pragma unroll
      for (int tt = 0; tt < 32; ++tt) acc[tt] += h2s[tt][j] * w;
    }
    for (int tt = 0; tt < 32; ++tt) {
      int t = tbase + tt;
      hfd[(size_t)d * kL + t] = acc[tt] * expf(-a * (float)t);
    }
  }
}

// ---------------- K4a: build compact worklist ----------------
// item = d | tile<<10 | sc<<13 | smax<<16   (smax = min(Td, (tile+1)*1024))
__global__ __launch_bounds__(768) void build_worklist(
    const float* __restrict__ log_decay, int* __restrict__ items,
    int* __restrict__ n_items) {
  __shared__ int cnt[768];
  const int d = threadIdx.x;
  float a = fabsf(log_decay[d]);
  int Td = (a * (float)kL <= 20.0f) ? kL : ((int)(20.0f / a) + 1);
  int smax_t[8];
  int c = 0;
#pragma unroll
  for (int tile = 0; tile < 8; ++tile) {
    int smax = min(Td, (tile + 1) * 1024);
    smax_t[tile] = smax;
    c += (smax + 1023) >> 10;
  }
  cnt[d] = c;
  __syncthreads();
  for (int off = 1; off < 768; off <<= 1) {
    int v = (d >= off) ? cnt[d - off] : 0;
    __syncthreads();
    cnt[d] += v;
    __syncthreads();
  }
  int base = cnt[d] - c;  // exclusive prefix
#pragma unroll
  for (int tile = 0; tile < 8; ++tile) {
    int nsc = (smax_t[tile] + 1023) >> 10;
    for (int sc = 0; sc < nsc; ++sc)
      items[base++] = d | (tile << 10) | (sc << 13) | (smax_t[tile] << 16);
  }
  if (d == 767) n_items[0] = cnt[767];
}

// ---------------- K4b: causal long conv over worklist (no LDS, no barriers) ----------------
// Each lane owns 4 outputs T..T+3 (T = t0 + 4*tid). Per 4 taps: one new
// aligned f16x4 global load per batch (u is L2/L3-resident), h via
// wave-uniform scalar loads. Sliding hi/lo register window:
//   acc.e += h[ss+q] * u[T+e-ss-q],  W = [lo | hi] around base = T - ss.
constexpr int SC = 1024;
__device__ __forceinline__ float4 ldu4(const f16* p) {
  f16x4 a = *(const f16x4*)(p);
  return make_float4((float)a[0], (float)a[1], (float)a[2], (float)a[3]);
}
__global__ __launch_bounds__(256) void long_conv_wl(
    const f16* __restrict__ u, const float* __restrict__ hfd,
    const int* __restrict__ items, const int* __restrict__ n_items,
    float* __restrict__ y) {
  const int tid = threadIdx.x;
  const int n = __builtin_amdgcn_readfirstlane(n_items[0]);
  for (int it = blockIdx.x; it < n; it += gridDim.x) {
    const int item = __builtin_amdgcn_readfirstlane(items[it]);
    const int d    = item & 1023;
    const int tile = (item >> 10) & 7;
    const int sc   = (item >> 13) & 7;
    const int smax = item >> 16;
    const int t0 = tile << 10;
    const int s_begin = sc << 10;
    const int s_end = min(s_begin + SC, smax);
    const f16* ub0 = u + (size_t)d * kL;           // b=0
    const f16* ub1 = u + (size_t)(kD + d) * kL;    // b=1
    const float* hb = hfd + (size_t)d * kL;
    const int T = t0 + 4 * tid;
    float4 acc0 = make_float4(0.f, 0.f, 0.f, 0.f);
    float4 acc1 = make_float4(0.f, 0.f, 0.f, 0.f);
    int base = T - s_begin;            // >= 0 always (s_begin <= t0)
    float4 hi0 = ldu4(ub0 + base);
    float4 hi1 = ldu4(ub1 + base);
    for (int ss = s_begin; ss < s_end; ss += 4) {
      const float4 h4 = *(const float4*)(hb + ss);   // wave-uniform -> s_load
      const int lobase = base - 4;
      float4 lo0, lo1;
      if (lobase >= 0) {
        lo0 = ldu4(ub0 + lobase);
        lo1 = ldu4(ub1 + lobase);
      } else {
        lo0 = make_float4(0.f, 0.f, 0.f, 0.f);
        lo1 = lo0;
      }
      acc0.x += h4.x * hi0.x; acc0.y += h4.x * hi0.y; acc0.z += h4.x * hi0.z; acc0.w += h4.x * hi0.w;
      acc0.x += h4.y * lo0.w; acc0.y += h4.y * hi0.x; acc0.z += h4.y * hi0.y; acc0.w += h4.y * hi0.z;
      acc0.x += h4.z * lo0.z; acc0.y += h4.z * lo0.w; acc0.z += h4.z * hi0.x; acc0.w += h4.z * hi0.y;
      acc0.x += h4.w * lo0.y; acc0.y += h4.w * lo0.z; acc0.z += h4.w * lo0.w; acc0.w += h4.w * hi0.x;
      acc1.x += h4.x * hi1.x; acc1.y += h4.x * hi1.y; acc1.z += h4.x * hi1.z; acc1.w += h4.x * hi1.w;
      acc1.x += h4.y * lo1.w; acc1.y += h4.y * hi1.x; acc1.z += h4.y * hi1.y; acc1.w += h4.y * hi1.z;
      acc1.x += h4.z * lo1.z; acc1.y += h4.z * lo1.w; acc1.z += h4.z * hi1.x; acc1.w += h4.z * hi1.y;
      acc1.x += h4.w * lo1.y; acc1.y += h4.w * lo1.z; acc1.z += h4.w * lo1.w; acc1.w += h4.w * hi1.x;
      hi0 = lo0;
      hi1 = lo1;
      base = lobase;
    }
    float* y0 = &y[(size_t)d * kL + t0 + 4 * tid];
    float* y1 = &y[(size_t)(kD + d) * kL + t0 + 4 * tid];
    if (smax <= SC) {  // sole writer (nsc == 1 for this tile)
      *(float4*)y0 = acc0;
      *(float4*)y1 = acc1;
    } else {
      atomicAdd(y0 + 0, acc0.x); atomicAdd(y0 + 1, acc0.y);
      atomicAdd(y0 + 2, acc0.z); atomicAdd(y0 + 3, acc0.w);
      atomicAdd(y1 + 0, acc1.x); atomicAdd(y1 + 1, acc1.y);
      atomicAdd(y1 + 2, acc1.z); atomicAdd(y1 + 3, acc1.w);
    }
  }
}

// ---------------- K5: gate + transpose  g16[b,t,d] = silu(q16[b,t,d]) * y[b,d,t] ----------------
__global__ __launch_bounds__(256) void gate_transpose(
    const f16* __restrict__ q, const float* __restrict__ y,
    f16* __restrict__ g) {
  __shared__ float ys[32][33];
  const int b  = blockIdx.z;
  const int t0 = blockIdx.x * 32;
  const int d0 = blockIdx.y * 32;
  const int tx = threadIdx.x;
  const int ty = threadIdx.y;
#pragma unroll
  for (int i = 0; i < 4; ++i) {
    int dd = ty + 8 * i;
    ys[dd][tx] = y[((size_t)b * kD + d0 + dd) * kL + t0 + tx];
  }
  __syncthreads();
  const f16* qb = q + (size_t)b * kL * kD;
#pragma unroll
  for (int i = 0; i < 4; ++i) {
    int t = t0 + ty + 8 * i;
    int d = d0 + tx;
    float qv = (float)qb[(size_t)t * kD + d];
    float sq = qv / (1.0f + expf(-qv));
    g[((size_t)b * kL + t) * kD + d] = (f16)(sq * ys[tx][ty + 8 * i]);
  }
}

}  // namespace

extern "C" void kernel_launch(void* const* d_in, const int* in_sizes, int n_in,
                              void* d_out, int out_size, void* d_ws, size_t ws_size,
                              hipStream_t stream) {
  const float* x          = (const float*)d_in[0];
  const float* in_proj_w  = (const float*)d_in[1];
  const float* sck_w      = (const float*)d_in[2];
  const float* sck_b      = (const float*)d_in[3];
  const float* scv_w      = (const float*)d_in[4];
  const float* scv_b      = (const float*)d_in[5];
  const float* mlp_w1     = (const float*)d_in[6];
  const float* mlp_b1     = (const float*)d_in[7];
  const float* mlp_w2     = (const float*)d_in[8];
  const float* mlp_b2     = (const float*)d_in[9];
  const float* mlp_w3     = (const float*)d_in[10];
  const float* mlp_b3     = (const float*)d_in[11];
  const float* log_decay  = (const float*)d_in[12];
  const float* out_proj_w = (const float*)d_in[13];
  float* out = (float*)d_out;

  // workspace layout (bytes), ~160 MB total
  char* base = (char*)d_ws;
  const size_t S1 = 25165824;   // q16  [B][L][D] fp16
  const size_t S2 = 50331648;   // kv16 [B][L][2D] fp16  -> later y [B][D][L] fp32
  const size_t S3 = 25165824;   // u16  [B][D][L] fp16
  const size_t S4 = 25165824;   // x16  [B][L][D] fp16   -> later g16
  const size_t S5 = 25165824;   // hfd  [D][L] fp32
  f16*   q16   = (f16*)base;
  f16*   kv16  = (f16*)(base + S1);
  float* y     = (float*)(base + S1);
  f16*   u16   = (f16*)(base + S1 + S2);
  f16*   x16   = (f16*)(base + S1 + S2 + S3);
  f16*   g16   = x16;
  float* hfd   = (float*)(base + S1 + S2 + S3 + S4);
  f16*   w16in = (f16*)(base + S1 + S2 + S3 + S4 + S5);
  f16*   w16out= w16in + (size_t)3 * kD * kD;
  int*   items = (int*)(w16out + (size_t)kD * kD);   // up to 64K ints
  int*   n_items = items + 65536;

  // K0: fp32 -> fp16 conversions
  {
    int n1 = kB * kL * kD;
    int n2 = 3 * kD * kD;
    int n3 = kD * kD;
    cvt_f32_f16<<<(n1 / 8 + 255) / 256, 256, 0, stream>>>(x, x16, n1);
    cvt_f32_f16<<<(n2 / 8 + 255) / 256, 256, 0, stream>>>(in_proj_w, w16in, n2);
    cvt_f32_f16<<<(n3 / 8 + 255) / 256, 256, 0, stream>>>(out_proj_w, w16out, n3);
  }

  // K1: {q16, kv16} = x16 @ w16in^T  (M=16384, N=2304, K=768)
  hgemm_qkv<<<dim3(18, 128), 256, 0, stream>>>(x16, w16in, q16, kv16, kB * kL);

  // K2: u16[b,d,t] = conv_k * conv_v
  dwconv_mul<<<dim3(kL / 32, kD / 32, kB), dim3(32, 8), 0, stream>>>(
      kv16, sck_w, sck_b, scv_w, scv_b, u16);

  // zero y (kv16 dead after K2; y overlays it)
  hipMemsetAsync(y, 0, (size_t)kB * kD * kL * sizeof(float), stream);

  // K3: filter hfd[d][t]
  hyena_filter<<<dim3(kL / 32), 256, 0, stream>>>(
      mlp_w1, mlp_b1, mlp_w2, mlp_b2, mlp_w3, mlp_b3, log_decay, hfd);

  // K4a: compact worklist
  build_worklist<<<1, 768, 0, stream>>>(log_decay, items, n_items);

  // K4b: y[b,d,t] += causal conv(u16, hfd) over worklist (both b per item)
  long_conv_wl<<<2048, 256, 0, stream>>>(u16, hfd, items, n_items, y);

  // K5: g16[b,t,d] = silu(q16) * y
  gate_transpose<<<dim3(kL / 32, kD / 32, kB), dim3(32, 8), 0, stream>>>(q16, y, g16);

  // K6: out = g16 @ w16out^T  (M=16384, N=768, K=768)
  hgemm_f32out<<<dim3(6, 128), 256, 0, stream>>>(g16, w16out, out, kB * kL, kD);
}

// Round 9
// 391.945 us; speedup vs baseline: 1.1030x; 1.1030x over previous
//
#include <hip/hip_runtime.h>
#include <math.h>

namespace {

constexpr int kB  = 2;
constexpr int kL  = 8192;
constexpr int kD  = 768;

typedef _Float16 f16;
typedef __attribute__((ext_vector_type(4))) _Float16 f16x4;
typedef __attribute__((ext_vector_type(8))) _Float16 f16x8;
typedef __attribute__((ext_vector_type(4))) float f32x4;

__device__ __forceinline__ void gload_lds16(const f16* g, f16* l) {
  __builtin_amdgcn_global_load_lds(
      (__attribute__((address_space(1))) void*)(g),
      (__attribute__((address_space(3))) void*)(l), 16, 0, 0);
}

// ---------------- K0: fp32 -> fp16 conversion ----------------
__global__ __launch_bounds__(256) void cvt_f32_f16(
    const float* __restrict__ s, f16* __restrict__ d, int n) {
  int t = blockIdx.x * 256 + threadIdx.x;
  int i = t * 8;
  if (i >= n) return;
  float4 a = *(const float4*)(s + i);
  float4 b = *(const float4*)(s + i + 4);
  f16x8 v;
  v[0] = (f16)a.x; v[1] = (f16)a.y; v[2] = (f16)a.z; v[3] = (f16)a.w;
  v[4] = (f16)b.x; v[5] = (f16)b.y; v[6] = (f16)b.z; v[7] = (f16)b.w;
  *(f16x8*)(d + i) = v;
}

// ---------------- K1: qkv projection (fp16 MFMA), split outputs ----------------
__global__ __launch_bounds__(256) void hgemm_qkv(
    const f16* __restrict__ A, const f16* __restrict__ W,
    f16* __restrict__ q16, f16* __restrict__ kv16, int M) {
  constexpr int K = 768;
  __shared__ f16 As[128 * 32];
  __shared__ f16 Bs[128 * 32];
  const int tid = threadIdx.x;
  const int bm = blockIdx.y, bn = blockIdx.x;
  const int lane = tid & 63;
  const int wv = tid >> 6;
  const int wr = wv >> 1, wc = wv & 1;
  const int fr = lane & 15, fq = lane >> 4;
  const int srow = tid >> 2;
  const int scol = (tid & 3) * 8;
  const f16* Ab = A + (size_t)bm * 128 * K;
  const f16* Wb = W + (size_t)bn * 128 * K;
  f32x4 acc[4][4];
#pragma unroll
  for (int m = 0; m < 4; ++m)
#pragma unroll
    for (int n = 0; n < 4; ++n)
#pragma unroll
      for (int j = 0; j < 4; ++j) acc[m][n][j] = 0.f;

  for (int k0 = 0; k0 < K; k0 += 32) {
#pragma unroll
    for (int i = 0; i < 2; ++i) {
      gload_lds16(Ab + (size_t)(i * 64 + srow) * K + k0 + scol, As + i * 2048 + wv * 512);
      gload_lds16(Wb + (size_t)(i * 64 + srow) * K + k0 + scol, Bs + i * 2048 + wv * 512);
    }
    __syncthreads();
    f16x8 af[4], bf[4];
#pragma unroll
    for (int m = 0; m < 4; ++m)
      af[m] = *(const f16x8*)&As[(wr * 64 + m * 16 + fr) * 32 + fq * 8];
#pragma unroll
    for (int n = 0; n < 4; ++n)
      bf[n] = *(const f16x8*)&Bs[(wc * 64 + n * 16 + fr) * 32 + fq * 8];
#pragma unroll
    for (int m = 0; m < 4; ++m)
#pragma unroll
      for (int n = 0; n < 4; ++n)
        acc[m][n] = __builtin_amdgcn_mfma_f32_16x16x32_f16(af[m], bf[n], acc[m][n], 0, 0, 0);
    __syncthreads();
  }
#pragma unroll
  for (int m = 0; m < 4; ++m) {
    int grow = bm * 128 + wr * 64 + m * 16 + fq * 4;
#pragma unroll
    for (int n = 0; n < 4; ++n) {
      int gcol = bn * 128 + wc * 64 + n * 16 + fr;
      f16* dst;
      int ldc, col;
      if (gcol < 768) { dst = q16; ldc = 768; col = gcol; }
      else            { dst = kv16; ldc = 1536; col = gcol - 768; }
#pragma unroll
      for (int j = 0; j < 4; ++j)
        dst[(size_t)(grow + j) * ldc + col] = (f16)acc[m][n][j];
    }
  }
}

// ---------------- K6: out = g16 @ w16out^T (fp16 MFMA, fp32 out) ----------------
__global__ __launch_bounds__(256) void hgemm_f32out(
    const f16* __restrict__ A, const f16* __restrict__ W,
    float* __restrict__ C, int M, int N) {
  constexpr int K = 768;
  __shared__ f16 As[128 * 32];
  __shared__ f16 Bs[128 * 32];
  const int tid = threadIdx.x;
  const int bm = blockIdx.y, bn = blockIdx.x;
  const int lane = tid & 63;
  const int wv = tid >> 6;
  const int wr = wv >> 1, wc = wv & 1;
  const int fr = lane & 15, fq = lane >> 4;
  const int srow = tid >> 2;
  const int scol = (tid & 3) * 8;
  const f16* Ab = A + (size_t)bm * 128 * K;
  const f16* Wb = W + (size_t)bn * 128 * K;
  f32x4 acc[4][4];
#pragma unroll
  for (int m = 0; m < 4; ++m)
#pragma unroll
    for (int n = 0; n < 4; ++n)
#pragma unroll
      for (int j = 0; j < 4; ++j) acc[m][n][j] = 0.f;

  for (int k0 = 0; k0 < K; k0 += 32) {
#pragma unroll
    for (int i = 0; i < 2; ++i) {
      gload_lds16(Ab + (size_t)(i * 64 + srow) * K + k0 + scol, As + i * 2048 + wv * 512);
      gload_lds16(Wb + (size_t)(i * 64 + srow) * K + k0 + scol, Bs + i * 2048 + wv * 512);
    }
    __syncthreads();
    f16x8 af[4], bf[4];
#pragma unroll
    for (int m = 0; m < 4; ++m)
      af[m] = *(const f16x8*)&As[(wr * 64 + m * 16 + fr) * 32 + fq * 8];
#pragma unroll
    for (int n = 0; n < 4; ++n)
      bf[n] = *(const f16x8*)&Bs[(wc * 64 + n * 16 + fr) * 32 + fq * 8];
#pragma unroll
    for (int m = 0; m < 4; ++m)
#pragma unroll
      for (int n = 0; n < 4; ++n)
        acc[m][n] = __builtin_amdgcn_mfma_f32_16x16x32_f16(af[m], bf[n], acc[m][n], 0, 0, 0);
    __syncthreads();
  }
#pragma unroll
  for (int m = 0; m < 4; ++m) {
    int grow = bm * 128 + wr * 64 + m * 16 + fq * 4;
#pragma unroll
    for (int n = 0; n < 4; ++n) {
      int gcol = bn * 128 + wc * 64 + n * 16 + fr;
#pragma unroll
      for (int j = 0; j < 4; ++j)
        C[(size_t)(grow + j) * N + gcol] = acc[m][n][j];
    }
  }
}

// ---------------- K2: depthwise causal conv(k=3) on k,v + product, transpose ----------------
__global__ __launch_bounds__(256) void dwconv_mul(
    const f16* __restrict__ kv,
    const float* __restrict__ sck_w, const float* __restrict__ sck_b,
    const float* __restrict__ scv_w, const float* __restrict__ scv_b,
    f16* __restrict__ u) {
  __shared__ float ks[34][33];
  __shared__ float vs[34][33];
  const int b  = blockIdx.z;
  const int d0 = blockIdx.y * 32;
  const int t0 = blockIdx.x * 32;
  const int tx = threadIdx.x;
  const int ty = threadIdx.y;
  const f16* base = kv + (size_t)b * kL * (2 * kD);
  for (int r = ty; r < 34; r += 8) {
    int t = t0 - 2 + r;
    float kk = 0.f, vv = 0.f;
    if (t >= 0) {
      kk = (float)base[(size_t)t * (2 * kD) + d0 + tx];
      vv = (float)base[(size_t)t * (2 * kD) + kD + d0 + tx];
    }
    ks[r][tx] = kk;
    vs[r][tx] = vv;
  }
  __syncthreads();
#pragma unroll
  for (int i = 0; i < 4; ++i) {
    int dd = ty + 8 * i;
    int d = d0 + dd;
    float kw0 = sck_w[d * 3 + 0], kw1 = sck_w[d * 3 + 1], kw2 = sck_w[d * 3 + 2];
    float vw0 = scv_w[d * 3 + 0], vw1 = scv_w[d * 3 + 1], vw2 = scv_w[d * 3 + 2];
    float kc = kw0 * ks[tx][dd] + kw1 * ks[tx + 1][dd] + kw2 * ks[tx + 2][dd] + sck_b[d];
    float vc = vw0 * vs[tx][dd] + vw1 * vs[tx + 1][dd] + vw2 * vs[tx + 2][dd] + scv_b[d];
    u[((size_t)b * kD + d) * kL + t0 + tx] = (f16)(kc * vc);
  }
}

// ---------------- K3: hyena filter  hfd[d][t] (fp32) ----------------
__global__ __launch_bounds__(256) void hyena_filter(
    const float* __restrict__ w1, const float* __restrict__ b1,
    const float* __restrict__ w2, const float* __restrict__ b2,
    const float* __restrict__ w3, const float* __restrict__ b3,
    const float* __restrict__ log_decay, float* __restrict__ hfd) {
  __shared__ float w1s[64 * 65];
  __shared__ float w2s[64 * 65];
  __shared__ float h2s[32][64];
  __shared__ float pe[64];
  __shared__ float h1v[64];
  const int tid = threadIdx.x;
  for (int i = tid; i < 64 * 64; i += 256) {
    w1s[(i >> 6) * 65 + (i & 63)] = w1[i];
    w2s[(i >> 6) * 65 + (i & 63)] = w2[i];
  }
  __syncthreads();
  const int tbase = blockIdx.x * 32;
  const float TWO_PI = 6.28318530717958647692f;
  for (int tt = 0; tt < 32; ++tt) {
    int t = tbase + tt;
    float tn = (float)t / 8191.0f;
    if (tid < 64) {
      float f = TWO_PI * (float)((tid & 31) + 1);
      pe[tid] = (tid < 32) ? sinf(tn * f) : cosf(tn * f);
    }
    __syncthreads();
    if (tid < 64) {
      float s = b1[tid];
      for (int j = 0; j < 64; ++j) s += pe[j] * w1s[tid * 65 + j];
      h1v[tid] = s / (1.0f + expf(-s));
    }
    __syncthreads();
    if (tid < 64) {
      float s = b2[tid];
      for (int j = 0; j < 64; ++j) s += h1v[j] * w2s[tid * 65 + j];
      h2s[tt][tid] = s / (1.0f + expf(-s));
    }
    __syncthreads();
  }
  for (int d = tid; d < kD; d += 256) {
    float a = fabsf(log_decay[d]);
    float bb = b3[d];
    float acc[32];
#pragma unroll
    for (int tt = 0; tt < 32; ++tt) acc[tt] = bb;
    for (int j = 0; j < 64; ++j) {
      float w = w3[d * 64 + j];
#pragma unroll
      for (int tt = 0; tt < 32; ++tt) acc[tt] += h2s[tt][j] * w;
    }
    for (int tt = 0; tt < 32; ++tt) {
      int t = tbase + tt;
      hfd[(size_t)d * kL + t] = acc[tt] * expf(-a * (float)t);
    }
  }
}

// ---------------- K4a: build compact worklist (wave-granular items) ----------------
// item = d | tc<<10 | sc<<15 ; t-chunk = 256 outputs, s-chunk = 256 taps.
// smax recomputed in-kernel from log_decay.
__global__ __launch_bounds__(768) void build_worklist(
    const float* __restrict__ log_decay, int* __restrict__ items,
    int* __restrict__ n_items) {
  __shared__ int cnt[768];
  const int d = threadIdx.x;
  float a = fabsf(log_decay[d]);
  int Td = (a * (float)kL <= 20.0f) ? kL : ((int)(20.0f / a) + 1);
  int c = 0;
#pragma unroll
  for (int tc = 0; tc < 32; ++tc) {
    int smax = min(Td, (tc + 1) * 256);
    c += (smax + 255) >> 8;
  }
  cnt[d] = c;
  __syncthreads();
  for (int off = 1; off < 768; off <<= 1) {
    int v = (d >= off) ? cnt[d - off] : 0;
    __syncthreads();
    cnt[d] += v;
    __syncthreads();
  }
  int base = cnt[d] - c;  // exclusive prefix
  for (int tc = 0; tc < 32; ++tc) {
    int smax = min(Td, (tc + 1) * 256);
    int nsc = (smax + 255) >> 8;
    for (int sc = 0; sc < nsc; ++sc)
      items[base++] = d | (tc << 10) | (sc << 15);
  }
  if (d == 767) n_items[0] = cnt[767];
}

// ---------------- K4b: causal long conv, one WAVE per item, prefetched ----------------
// Lane owns 4 outputs T..T+3 (T = t0 + 4*lane). Per 4 taps: one new aligned
// 8B load per batch, next iteration's loads issued BEFORE current FMAs.
constexpr int TC = 256;
__device__ __forceinline__ float4 ldu4(const f16* p) {
  f16x4 a = *(const f16x4*)(p);
  return make_float4((float)a[0], (float)a[1], (float)a[2], (float)a[3]);
}
__device__ __forceinline__ float4 ldz(const f16* p, int off) {
  // off is a multiple of 4; whole quad valid iff off >= 0. Memory at small
  // negative offsets is valid workspace (zero-selected before use).
  f16x4 a = *(const f16x4*)(p + off);
  float4 v = make_float4((float)a[0], (float)a[1], (float)a[2], (float)a[3]);
  if (off < 0) v = make_float4(0.f, 0.f, 0.f, 0.f);
  return v;
}
__global__ __launch_bounds__(256) void long_conv_wl(
    const f16* __restrict__ u, const float* __restrict__ hfd,
    const float* __restrict__ log_decay,
    const int* __restrict__ items, const int* __restrict__ n_items,
    float* __restrict__ y) {
  const int lane = threadIdx.x & 63;
  const int wid  = threadIdx.x >> 6;
  const int n = __builtin_amdgcn_readfirstlane(n_items[0]);
  for (int it = blockIdx.x * 4 + wid; it < n; it += gridDim.x * 4) {
    const int item = __builtin_amdgcn_readfirstlane(items[it]);
    const int d  = item & 1023;
    const int tc = (item >> 10) & 31;
    const int sc = item >> 15;
    const float a = fabsf(log_decay[d]);
    const int Td = (a * (float)kL <= 20.0f) ? kL : ((int)(20.0f / a) + 1);
    const int t0 = tc << 8;
    const int smax = min(Td, t0 + TC);
    const int s_begin = sc << 8;
    const int s_end = min(s_begin + TC, smax);
    const f16* ub0 = u + (size_t)d * kL;           // b=0
    const f16* ub1 = u + (size_t)(kD + d) * kL;    // b=1
    const float* hb = hfd + (size_t)d * kL;
    const int T = t0 + 4 * lane;
    float4 acc0 = make_float4(0.f, 0.f, 0.f, 0.f);
    float4 acc1 = make_float4(0.f, 0.f, 0.f, 0.f);
    int base = T - s_begin;            // >= 0 (s_begin <= t0 <= T)
    float4 hi0 = ldu4(ub0 + base);
    float4 hi1 = ldu4(ub1 + base);
    float4 lo0 = ldz(ub0, base - 4);
    float4 lo1 = ldz(ub1, base - 4);
    float4 h4  = *(const float4*)(hb + s_begin);   // wave-uniform -> s_load
    for (int ss = s_begin; ss < s_end; ss += 4) {
      // prefetch next iteration (overreads are valid memory; unused/zeroed)
      const int nb = base - 8;
      float4 nlo0 = ldz(ub0, nb);
      float4 nlo1 = ldz(ub1, nb);
      float4 nh   = *(const float4*)(hb + ss + 4);
      // current FMAs
      acc0.x += h4.x * hi0.x; acc0.y += h4.x * hi0.y; acc0.z += h4.x * hi0.z; acc0.w += h4.x * hi0.w;
      acc0.x += h4.y * lo0.w; acc0.y += h4.y * hi0.x; acc0.z += h4.y * hi0.y; acc0.w += h4.y * hi0.z;
      acc0.x += h4.z * lo0.z; acc0.y += h4.z * lo0.w; acc0.z += h4.z * hi0.x; acc0.w += h4.z * hi0.y;
      acc0.x += h4.w * lo0.y; acc0.y += h4.w * lo0.z; acc0.z += h4.w * lo0.w; acc0.w += h4.w * hi0.x;
      acc1.x += h4.x * hi1.x; acc1.y += h4.x * hi1.y; acc1.z += h4.x * hi1.z; acc1.w += h4.x * hi1.w;
      acc1.x += h4.y * lo1.w; acc1.y += h4.y * hi1.x; acc1.z += h4.y * hi1.y; acc1.w += h4.y * hi1.z;
      acc1.x += h4.z * lo1.z; acc1.y += h4.z * lo1.w; acc1.z += h4.z * hi1.x; acc1.w += h4.z * hi1.y;
      acc1.x += h4.w * lo1.y; acc1.y += h4.w * lo1.z; acc1.z += h4.w * lo1.w; acc1.w += h4.w * hi1.x;
      hi0 = lo0; lo0 = nlo0;
      hi1 = lo1; lo1 = nlo1;
      h4 = nh;
      base -= 4;
    }
    float* y0 = &y[(size_t)d * kL + t0 + 4 * lane];
    float* y1 = &y[(size_t)(kD + d) * kL + t0 + 4 * lane];
    if (smax <= TC) {  // sole writer for this (d, t-chunk)
      *(float4*)y0 = acc0;
      *(float4*)y1 = acc1;
    } else {
      atomicAdd(y0 + 0, acc0.x); atomicAdd(y0 + 1, acc0.y);
      atomicAdd(y0 + 2, acc0.z); atomicAdd(y0 + 3, acc0.w);
      atomicAdd(y1 + 0, acc1.x); atomicAdd(y1 + 1, acc1.y);
      atomicAdd(y1 + 2, acc1.z); atomicAdd(y1 + 3, acc1.w);
    }
  }
}

// ---------------- K5: gate + transpose  g16[b,t,d] = silu(q16[b,t,d]) * y[b,d,t] ----------------
__global__ __launch_bounds__(256) void gate_transpose(
    const f16* __restrict__ q, const float* __restrict__ y,
    f16* __restrict__ g) {
  __shared__ float ys[32][33];
  const int b  = blockIdx.z;
  const int t0 = blockIdx.x * 32;
  const int d0 = blockIdx.y * 32;
  const int tx = threadIdx.x;
  const int ty = threadIdx.y;
#pragma unroll
  for (int i = 0; i < 4; ++i) {
    int dd = ty + 8 * i;
    ys[dd][tx] = y[((size_t)b * kD + d0 + dd) * kL + t0 + tx];
  }
  __syncthreads();
  const f16* qb = q + (size_t)b * kL * kD;
#pragma unroll
  for (int i = 0; i < 4; ++i) {
    int t = t0 + ty + 8 * i;
    int d = d0 + tx;
    float qv = (float)qb[(size_t)t * kD + d];
    float sq = qv / (1.0f + expf(-qv));
    g[((size_t)b * kL + t) * kD + d] = (f16)(sq * ys[tx][ty + 8 * i]);
  }
}

}  // namespace

extern "C" void kernel_launch(void* const* d_in, const int* in_sizes, int n_in,
                              void* d_out, int out_size, void* d_ws, size_t ws_size,
                              hipStream_t stream) {
  const float* x          = (const float*)d_in[0];
  const float* in_proj_w  = (const float*)d_in[1];
  const float* sck_w      = (const float*)d_in[2];
  const float* sck_b      = (const float*)d_in[3];
  const float* scv_w      = (const float*)d_in[4];
  const float* scv_b      = (const float*)d_in[5];
  const float* mlp_w1     = (const float*)d_in[6];
  const float* mlp_b1     = (const float*)d_in[7];
  const float* mlp_w2     = (const float*)d_in[8];
  const float* mlp_b2     = (const float*)d_in[9];
  const float* mlp_w3     = (const float*)d_in[10];
  const float* mlp_b3     = (const float*)d_in[11];
  const float* log_decay  = (const float*)d_in[12];
  const float* out_proj_w = (const float*)d_in[13];
  float* out = (float*)d_out;

  // workspace layout (bytes), ~158 MB total
  char* base = (char*)d_ws;
  const size_t S1 = 25165824;   // q16  [B][L][D] fp16
  const size_t S2 = 50331648;   // kv16 [B][L][2D] fp16  -> later y [B][D][L] fp32
  const size_t S3 = 25165824;   // u16  [B][D][L] fp16
  const size_t S4 = 25165824;   // x16  [B][L][D] fp16   -> later g16
  const size_t S5 = 25165824;   // hfd  [D][L] fp32
  f16*   q16   = (f16*)base;
  f16*   kv16  = (f16*)(base + S1);
  float* y     = (float*)(base + S1);
  f16*   u16   = (f16*)(base + S1 + S2);
  f16*   x16   = (f16*)(base + S1 + S2 + S3);
  f16*   g16   = x16;
  float* hfd   = (float*)(base + S1 + S2 + S3 + S4);
  f16*   w16in = (f16*)(base + S1 + S2 + S3 + S4 + S5);
  f16*   w16out= w16in + (size_t)3 * kD * kD;
  int*   items = (int*)(w16out + (size_t)kD * kD);   // 256K ints (1 MB)
  int*   n_items = items + 262144;

  // K0: fp32 -> fp16 conversions
  {
    int n1 = kB * kL * kD;
    int n2 = 3 * kD * kD;
    int n3 = kD * kD;
    cvt_f32_f16<<<(n1 / 8 + 255) / 256, 256, 0, stream>>>(x, x16, n1);
    cvt_f32_f16<<<(n2 / 8 + 255) / 256, 256, 0, stream>>>(in_proj_w, w16in, n2);
    cvt_f32_f16<<<(n3 / 8 + 255) / 256, 256, 0, stream>>>(out_proj_w, w16out, n3);
  }

  // K1: {q16, kv16} = x16 @ w16in^T  (M=16384, N=2304, K=768)
  hgemm_qkv<<<dim3(18, 128), 256, 0, stream>>>(x16, w16in, q16, kv16, kB * kL);

  // K2: u16[b,d,t] = conv_k * conv_v
  dwconv_mul<<<dim3(kL / 32, kD / 32, kB), dim3(32, 8), 0, stream>>>(
      kv16, sck_w, sck_b, scv_w, scv_b, u16);

  // zero y (kv16 dead after K2; y overlays it)
  hipMemsetAsync(y, 0, (size_t)kB * kD * kL * sizeof(float), stream);

  // K3: filter hfd[d][t]
  hyena_filter<<<dim3(kL / 32), 256, 0, stream>>>(
      mlp_w1, mlp_b1, mlp_w2, mlp_b2, mlp_w3, mlp_b3, log_decay, hfd);

  // K4a: compact wave-granular worklist
  build_worklist<<<1, 768, 0, stream>>>(log_decay, items, n_items);

  // K4b: y[b,d,t] += causal conv(u16, hfd); one wave per item, prefetched
  long_conv_wl<<<2048, 256, 0, stream>>>(u16, hfd, log_decay, items, n_items, y);

  // K5: g16[b,t,d] = silu(q16) * y
  gate_transpose<<<dim3(kL / 32, kD / 32, kB), dim3(32, 8), 0, stream>>>(q16, y, g16);

  // K6: out = g16 @ w16out^T  (M=16384, N=768, K=768)
  hgemm_f32out<<<dim3(6, 128), 256, 0, stream>>>(g16, w16out, out, kB * kL, kD);
}

// Round 10
// 367.178 us; speedup vs baseline: 1.1774x; 1.0675x over previous
//
#include <hip/hip_runtime.h>
#include <math.h>

namespace {

constexpr int kB  = 2;
constexpr int kL  = 8192;
constexpr int kD  = 768;

typedef _Float16 f16;
typedef __attribute__((ext_vector_type(4))) _Float16 f16x4;
typedef __attribute__((ext_vector_type(8))) _Float16 f16x8;
typedef __attribute__((ext_vector_type(4))) float f32x4;

__device__ __forceinline__ void gload_lds16(const f16* g, f16* l) {
  __builtin_amdgcn_global_load_lds(
      (__attribute__((address_space(1))) void*)(g),
      (__attribute__((address_space(3))) void*)(l), 16, 0, 0);
}

// ---------------- K0: fp32 -> fp16 conversion ----------------
__global__ __launch_bounds__(256) void cvt_f32_f16(
    const float* __restrict__ s, f16* __restrict__ d, int n) {
  int t = blockIdx.x * 256 + threadIdx.x;
  int i = t * 8;
  if (i >= n) return;
  float4 a = *(const float4*)(s + i);
  float4 b = *(const float4*)(s + i + 4);
  f16x8 v;
  v[0] = (f16)a.x; v[1] = (f16)a.y; v[2] = (f16)a.z; v[3] = (f16)a.w;
  v[4] = (f16)b.x; v[5] = (f16)b.y; v[6] = (f16)b.z; v[7] = (f16)b.w;
  *(f16x8*)(d + i) = v;
}

// ---------------- K1: qkv projection (fp16 MFMA), split outputs ----------------
__global__ __launch_bounds__(256) void hgemm_qkv(
    const f16* __restrict__ A, const f16* __restrict__ W,
    f16* __restrict__ q16, f16* __restrict__ kv16, int M) {
  constexpr int K = 768;
  __shared__ f16 As[128 * 32];
  __shared__ f16 Bs[128 * 32];
  const int tid = threadIdx.x;
  const int bm = blockIdx.y, bn = blockIdx.x;
  const int lane = tid & 63;
  const int wv = tid >> 6;
  const int wr = wv >> 1, wc = wv & 1;
  const int fr = lane & 15, fq = lane >> 4;
  const int srow = tid >> 2;
  const int scol = (tid & 3) * 8;
  const f16* Ab = A + (size_t)bm * 128 * K;
  const f16* Wb = W + (size_t)bn * 128 * K;
  f32x4 acc[4][4];
#pragma unroll
  for (int m = 0; m < 4; ++m)
#pragma unroll
    for (int n = 0; n < 4; ++n)
#pragma unroll
      for (int j = 0; j < 4; ++j) acc[m][n][j] = 0.f;

  for (int k0 = 0; k0 < K; k0 += 32) {
#pragma unroll
    for (int i = 0; i < 2; ++i) {
      gload_lds16(Ab + (size_t)(i * 64 + srow) * K + k0 + scol, As + i * 2048 + wv * 512);
      gload_lds16(Wb + (size_t)(i * 64 + srow) * K + k0 + scol, Bs + i * 2048 + wv * 512);
    }
    __syncthreads();
    f16x8 af[4], bf[4];
#pragma unroll
    for (int m = 0; m < 4; ++m)
      af[m] = *(const f16x8*)&As[(wr * 64 + m * 16 + fr) * 32 + fq * 8];
#pragma unroll
    for (int n = 0; n < 4; ++n)
      bf[n] = *(const f16x8*)&Bs[(wc * 64 + n * 16 + fr) * 32 + fq * 8];
#pragma unroll
    for (int m = 0; m < 4; ++m)
#pragma unroll
      for (int n = 0; n < 4; ++n)
        acc[m][n] = __builtin_amdgcn_mfma_f32_16x16x32_f16(af[m], bf[n], acc[m][n], 0, 0, 0);
    __syncthreads();
  }
#pragma unroll
  for (int m = 0; m < 4; ++m) {
    int grow = bm * 128 + wr * 64 + m * 16 + fq * 4;
#pragma unroll
    for (int n = 0; n < 4; ++n) {
      int gcol = bn * 128 + wc * 64 + n * 16 + fr;
      f16* dst;
      int ldc, col;
      if (gcol < 768) { dst = q16; ldc = 768; col = gcol; }
      else            { dst = kv16; ldc = 1536; col = gcol - 768; }
#pragma unroll
      for (int j = 0; j < 4; ++j)
        dst[(size_t)(grow + j) * ldc + col] = (f16)acc[m][n][j];
    }
  }
}

// ---------------- K6: out = g16 @ w16out^T (fp16 MFMA, fp32 out) ----------------
__global__ __launch_bounds__(256) void hgemm_f32out(
    const f16* __restrict__ A, const f16* __restrict__ W,
    float* __restrict__ C, int M, int N) {
  constexpr int K = 768;
  __shared__ f16 As[128 * 32];
  __shared__ f16 Bs[128 * 32];
  const int tid = threadIdx.x;
  const int bm = blockIdx.y, bn = blockIdx.x;
  const int lane = tid & 63;
  const int wv = tid >> 6;
  const int wr = wv >> 1, wc = wv & 1;
  const int fr = lane & 15, fq = lane >> 4;
  const int srow = tid >> 2;
  const int scol = (tid & 3) * 8;
  const f16* Ab = A + (size_t)bm * 128 * K;
  const f16* Wb = W + (size_t)bn * 128 * K;
  f32x4 acc[4][4];
#pragma unroll
  for (int m = 0; m < 4; ++m)
#pragma unroll
    for (int n = 0; n < 4; ++n)
#pragma unroll
      for (int j = 0; j < 4; ++j) acc[m][n][j] = 0.f;

  for (int k0 = 0; k0 < K; k0 += 32) {
#pragma unroll
    for (int i = 0; i < 2; ++i) {
      gload_lds16(Ab + (size_t)(i * 64 + srow) * K + k0 + scol, As + i * 2048 + wv * 512);
      gload_lds16(Wb + (size_t)(i * 64 + srow) * K + k0 + scol, Bs + i * 2048 + wv * 512);
    }
    __syncthreads();
    f16x8 af[4], bf[4];
#pragma unroll
    for (int m = 0; m < 4; ++m)
      af[m] = *(const f16x8*)&As[(wr * 64 + m * 16 + fr) * 32 + fq * 8];
#pragma unroll
    for (int n = 0; n < 4; ++n)
      bf[n] = *(const f16x8*)&Bs[(wc * 64 + n * 16 + fr) * 32 + fq * 8];
#pragma unroll
    for (int m = 0; m < 4; ++m)
#pragma unroll
      for (int n = 0; n < 4; ++n)
        acc[m][n] = __builtin_amdgcn_mfma_f32_16x16x32_f16(af[m], bf[n], acc[m][n], 0, 0, 0);
    __syncthreads();
  }
#pragma unroll
  for (int m = 0; m < 4; ++m) {
    int grow = bm * 128 + wr * 64 + m * 16 + fq * 4;
#pragma unroll
    for (int n = 0; n < 4; ++n) {
      int gcol = bn * 128 + wc * 64 + n * 16 + fr;
#pragma unroll
      for (int j = 0; j < 4; ++j)
        C[(size_t)(grow + j) * N + gcol] = acc[m][n][j];
    }
  }
}

// ---------------- K2: depthwise causal conv(k=3) on k,v + product, transpose ----------------
__global__ __launch_bounds__(256) void dwconv_mul(
    const f16* __restrict__ kv,
    const float* __restrict__ sck_w, const float* __restrict__ sck_b,
    const float* __restrict__ scv_w, const float* __restrict__ scv_b,
    f16* __restrict__ u) {
  __shared__ float ks[34][33];
  __shared__ float vs[34][33];
  const int b  = blockIdx.z;
  const int d0 = blockIdx.y * 32;
  const int t0 = blockIdx.x * 32;
  const int tx = threadIdx.x;
  const int ty = threadIdx.y;
  const f16* base = kv + (size_t)b * kL * (2 * kD);
  for (int r = ty; r < 34; r += 8) {
    int t = t0 - 2 + r;
    float kk = 0.f, vv = 0.f;
    if (t >= 0) {
      kk = (float)base[(size_t)t * (2 * kD) + d0 + tx];
      vv = (float)base[(size_t)t * (2 * kD) + kD + d0 + tx];
    }
    ks[r][tx] = kk;
    vs[r][tx] = vv;
  }
  __syncthreads();
#pragma unroll
  for (int i = 0; i < 4; ++i) {
    int dd = ty + 8 * i;
    int d = d0 + dd;
    float kw0 = sck_w[d * 3 + 0], kw1 = sck_w[d * 3 + 1], kw2 = sck_w[d * 3 + 2];
    float vw0 = scv_w[d * 3 + 0], vw1 = scv_w[d * 3 + 1], vw2 = scv_w[d * 3 + 2];
    float kc = kw0 * ks[tx][dd] + kw1 * ks[tx + 1][dd] + kw2 * ks[tx + 2][dd] + sck_b[d];
    float vc = vw0 * vs[tx][dd] + vw1 * vs[tx + 1][dd] + vw2 * vs[tx + 2][dd] + scv_b[d];
    u[((size_t)b * kD + d) * kL + t0 + tx] = (f16)(kc * vc);
  }
}

// ---------------- K3: hyena filter  hfd[d][t] (fp32) ----------------
__global__ __launch_bounds__(256) void hyena_filter(
    const float* __restrict__ w1, const float* __restrict__ b1,
    const float* __restrict__ w2, const float* __restrict__ b2,
    const float* __restrict__ w3, const float* __restrict__ b3,
    const float* __restrict__ log_decay, float* __restrict__ hfd) {
  __shared__ float w1s[64 * 65];
  __shared__ float w2s[64 * 65];
  __shared__ float h2s[32][64];
  __shared__ float pe[64];
  __shared__ float h1v[64];
  const int tid = threadIdx.x;
  for (int i = tid; i < 64 * 64; i += 256) {
    w1s[(i >> 6) * 65 + (i & 63)] = w1[i];
    w2s[(i >> 6) * 65 + (i & 63)] = w2[i];
  }
  __syncthreads();
  const int tbase = blockIdx.x * 32;
  const float TWO_PI = 6.28318530717958647692f;
  for (int tt = 0; tt < 32; ++tt) {
    int t = tbase + tt;
    float tn = (float)t / 8191.0f;
    if (tid < 64) {
      float f = TWO_PI * (float)((tid & 31) + 1);
      pe[tid] = (tid < 32) ? sinf(tn * f) : cosf(tn * f);
    }
    __syncthreads();
    if (tid < 64) {
      float s = b1[tid];
      for (int j = 0; j < 64; ++j) s += pe[j] * w1s[tid * 65 + j];
      h1v[tid] = s / (1.0f + expf(-s));
    }
    __syncthreads();
    if (tid < 64) {
      float s = b2[tid];
      for (int j = 0; j < 64; ++j) s += h1v[j] * w2s[tid * 65 + j];
      h2s[tt][tid] = s / (1.0f + expf(-s));
    }
    __syncthreads();
  }
  for (int d = tid; d < kD; d += 256) {
    float a = fabsf(log_decay[d]);
    float bb = b3[d];
    float acc[32];
#pragma unroll
    for (int tt = 0; tt < 32; ++tt) acc[tt] = bb;
    for (int j = 0; j < 64; ++j) {
      float w = w3[d * 64 + j];
#pragma unroll
      for (int tt = 0; tt < 32; ++tt) acc[tt] += h2s[tt][j] * w;
    }
    for (int tt = 0; tt < 32; ++tt) {
      int t = tbase + tt;
      hfd[(size_t)d * kL + t] = acc[tt] * expf(-a * (float)t);
    }
  }
}

// ---------------- truncation length (shared by K4a/K4b; MUST match) ----------------
__device__ __forceinline__ int trunc_len(float a) {
  int Td = (a * (float)kL <= 16.0f) ? kL : ((int)(16.0f / a) + 1);
  Td = (Td + 7) & ~7;            // multiple of 8 -> s_end always multiple of 8
  return min(Td, kL);
}

// ---------------- K4a: build compact worklist (wave-granular items) ----------------
// item = d | tc<<10 | sc<<15 ; t-chunk = 256 outputs, s-chunk = 256 taps.
__global__ __launch_bounds__(768) void build_worklist(
    const float* __restrict__ log_decay, int* __restrict__ items,
    int* __restrict__ n_items) {
  __shared__ int cnt[768];
  const int d = threadIdx.x;
  float a = fabsf(log_decay[d]);
  int Td = trunc_len(a);
  int c = 0;
#pragma unroll
  for (int tc = 0; tc < 32; ++tc) {
    int smax = min(Td, (tc + 1) * 256);
    c += (smax + 255) >> 8;
  }
  cnt[d] = c;
  __syncthreads();
  for (int off = 1; off < 768; off <<= 1) {
    int v = (d >= off) ? cnt[d - off] : 0;
    __syncthreads();
    cnt[d] += v;
    __syncthreads();
  }
  int base = cnt[d] - c;  // exclusive prefix
  for (int tc = 0; tc < 32; ++tc) {
    int smax = min(Td, (tc + 1) * 256);
    int nsc = (smax + 255) >> 8;
    for (int sc = 0; sc < nsc; ++sc)
      items[base++] = d | (tc << 10) | (sc << 15);
  }
  if (d == 767) n_items[0] = cnt[767];
}

// ---------------- K4b: causal long conv, one WAVE per item ----------------
// Lane owns 4 outputs T..T+3. 8 taps/iteration via a 12-element sliding
// register window (A=[base..base+3], B=[base-4..base-1], C=[base-8..base-5]);
// u stays f16 in registers (v_fma_mix: acc_f32 += h_f32 * u_f16).
constexpr int TC = 256;
__device__ __forceinline__ f16x4 ld4(const f16* p, int off) {
  return *(const f16x4*)(p + off);
}
__device__ __forceinline__ f16x4 ld4z(const f16* p, int off) {
  // off is a multiple of 4; quad valid iff off >= 0. Small negative offsets
  // read valid workspace bytes (result zero-selected).
  f16x4 v = *(const f16x4*)(p + off);
  if (off < 0) v = (f16x4){};
  return v;
}
#define TAPS8(acc, Aq, Bq, Cq)                                                                                       \
  acc.x += h4a.x * (float)Aq[0]; acc.y += h4a.x * (float)Aq[1]; acc.z += h4a.x * (float)Aq[2]; acc.w += h4a.x * (float)Aq[3]; \
  acc.x += h4a.y * (float)Bq[3]; acc.y += h4a.y * (float)Aq[0]; acc.z += h4a.y * (float)Aq[1]; acc.w += h4a.y * (float)Aq[2]; \
  acc.x += h4a.z * (float)Bq[2]; acc.y += h4a.z * (float)Bq[3]; acc.z += h4a.z * (float)Aq[0]; acc.w += h4a.z * (float)Aq[1]; \
  acc.x += h4a.w * (float)Bq[1]; acc.y += h4a.w * (float)Bq[2]; acc.z += h4a.w * (float)Bq[3]; acc.w += h4a.w * (float)Aq[0]; \
  acc.x += h4b.x * (float)Bq[0]; acc.y += h4b.x * (float)Bq[1]; acc.z += h4b.x * (float)Bq[2]; acc.w += h4b.x * (float)Bq[3]; \
  acc.x += h4b.y * (float)Cq[3]; acc.y += h4b.y * (float)Bq[0]; acc.z += h4b.y * (float)Bq[1]; acc.w += h4b.y * (float)Bq[2]; \
  acc.x += h4b.z * (float)Cq[2]; acc.y += h4b.z * (float)Cq[3]; acc.z += h4b.z * (float)Bq[0]; acc.w += h4b.z * (float)Bq[1]; \
  acc.x += h4b.w * (float)Cq[1]; acc.y += h4b.w * (float)Cq[2]; acc.z += h4b.w * (float)Cq[3]; acc.w += h4b.w * (float)Bq[0];
__global__ __launch_bounds__(256) void long_conv_wl(
    const f16* __restrict__ u, const float* __restrict__ hfd,
    const float* __restrict__ log_decay,
    const int* __restrict__ items, const int* __restrict__ n_items,
    float* __restrict__ y) {
  const int lane = threadIdx.x & 63;
  const int wid  = threadIdx.x >> 6;
  const int n = __builtin_amdgcn_readfirstlane(n_items[0]);
  for (int it = blockIdx.x * 4 + wid; it < n; it += gridDim.x * 4) {
    const int item = __builtin_amdgcn_readfirstlane(items[it]);
    const int d  = item & 1023;
    const int tc = (item >> 10) & 31;
    const int sc = item >> 15;
    const float a = fabsf(log_decay[d]);
    const int Td = trunc_len(a);
    const int t0 = tc << 8;
    const int smax = min(Td, t0 + TC);
    const int s_begin = sc << 8;
    const int s_end = min(s_begin + TC, smax);
    const f16* ub0 = u + (size_t)d * kL;           // b=0
    const f16* ub1 = u + (size_t)(kD + d) * kL;    // b=1
    const float* hb = hfd + (size_t)d * kL;
    const int T = t0 + 4 * lane;
    float4 acc0 = make_float4(0.f, 0.f, 0.f, 0.f);
    float4 acc1 = make_float4(0.f, 0.f, 0.f, 0.f);
    int base = T - s_begin;            // >= 0 (s_begin <= t0 <= T), mult of 4
    f16x4 A0 = ld4(ub0, base),      A1 = ld4(ub1, base);
    f16x4 B0 = ld4z(ub0, base - 4), B1 = ld4z(ub1, base - 4);
    f16x4 C0 = ld4z(ub0, base - 8), C1 = ld4z(ub1, base - 8);
    float4 h4a = *(const float4*)(hb + s_begin);       // wave-uniform
    float4 h4b = *(const float4*)(hb + s_begin + 4);
    for (int ss = s_begin; ss < s_end; ss += 8) {
      // prefetch next iteration's window + h before the FMA block
      const int nb = base - 8;
      f16x4 nB0 = ld4z(ub0, nb - 4), nB1 = ld4z(ub1, nb - 4);
      f16x4 nC0 = ld4z(ub0, nb - 8), nC1 = ld4z(ub1, nb - 8);
      float4 nha = *(const float4*)(hb + ss + 8);
      float4 nhb = *(const float4*)(hb + ss + 12);
      TAPS8(acc0, A0, B0, C0);
      TAPS8(acc1, A1, B1, C1);
      A0 = C0; B0 = nB0; C0 = nC0;
      A1 = C1; B1 = nB1; C1 = nC1;
      h4a = nha; h4b = nhb;
      base = nb;
    }
    float* y0 = &y[(size_t)d * kL + t0 + 4 * lane];
    float* y1 = &y[(size_t)(kD + d) * kL + t0 + 4 * lane];
    if (smax <= TC) {  // sole writer for this (d, t-chunk)
      *(float4*)y0 = acc0;
      *(float4*)y1 = acc1;
    } else {
      atomicAdd(y0 + 0, acc0.x); atomicAdd(y0 + 1, acc0.y);
      atomicAdd(y0 + 2, acc0.z); atomicAdd(y0 + 3, acc0.w);
      atomicAdd(y1 + 0, acc1.x); atomicAdd(y1 + 1, acc1.y);
      atomicAdd(y1 + 2, acc1.z); atomicAdd(y1 + 3, acc1.w);
    }
  }
}

// ---------------- K5: gate + transpose  g16[b,t,d] = silu(q16[b,t,d]) * y[b,d,t] ----------------
__global__ __launch_bounds__(256) void gate_transpose(
    const f16* __restrict__ q, const float* __restrict__ y,
    f16* __restrict__ g) {
  __shared__ float ys[32][33];
  const int b  = blockIdx.z;
  const int t0 = blockIdx.x * 32;
  const int d0 = blockIdx.y * 32;
  const int tx = threadIdx.x;
  const int ty = threadIdx.y;
#pragma unroll
  for (int i = 0; i < 4; ++i) {
    int dd = ty + 8 * i;
    ys[dd][tx] = y[((size_t)b * kD + d0 + dd) * kL + t0 + tx];
  }
  __syncthreads();
  const f16* qb = q + (size_t)b * kL * kD;
#pragma unroll
  for (int i = 0; i < 4; ++i) {
    int t = t0 + ty + 8 * i;
    int d = d0 + tx;
    float qv = (float)qb[(size_t)t * kD + d];
    float sq = qv / (1.0f + expf(-qv));
    g[((size_t)b * kL + t) * kD + d] = (f16)(sq * ys[tx][ty + 8 * i]);
  }
}

}  // namespace

extern "C" void kernel_launch(void* const* d_in, const int* in_sizes, int n_in,
                              void* d_out, int out_size, void* d_ws, size_t ws_size,
                              hipStream_t stream) {
  const float* x          = (const float*)d_in[0];
  const float* in_proj_w  = (const float*)d_in[1];
  const float* sck_w      = (const float*)d_in[2];
  const float* sck_b      = (const float*)d_in[3];
  const float* scv_w      = (const float*)d_in[4];
  const float* scv_b      = (const float*)d_in[5];
  const float* mlp_w1     = (const float*)d_in[6];
  const float* mlp_b1     = (const float*)d_in[7];
  const float* mlp_w2     = (const float*)d_in[8];
  const float* mlp_b2     = (const float*)d_in[9];
  const float* mlp_w3     = (const float*)d_in[10];
  const float* mlp_b3     = (const float*)d_in[11];
  const float* log_decay  = (const float*)d_in[12];
  const float* out_proj_w = (const float*)d_in[13];
  float* out = (float*)d_out;

  // workspace layout (bytes), ~158 MB total
  char* base = (char*)d_ws;
  const size_t S1 = 25165824;   // q16  [B][L][D] fp16
  const size_t S2 = 50331648;   // kv16 [B][L][2D] fp16  -> later y [B][D][L] fp32
  const size_t S3 = 25165824;   // u16  [B][D][L] fp16
  const size_t S4 = 25165824;   // x16  [B][L][D] fp16   -> later g16
  const size_t S5 = 25165824;   // hfd  [D][L] fp32
  f16*   q16   = (f16*)base;
  f16*   kv16  = (f16*)(base + S1);
  float* y     = (float*)(base + S1);
  f16*   u16   = (f16*)(base + S1 + S2);
  f16*   x16   = (f16*)(base + S1 + S2 + S3);
  f16*   g16   = x16;
  float* hfd   = (float*)(base + S1 + S2 + S3 + S4);
  f16*   w16in = (f16*)(base + S1 + S2 + S3 + S4 + S5);
  f16*   w16out= w16in + (size_t)3 * kD * kD;
  int*   items = (int*)(w16out + (size_t)kD * kD);   // 256K ints (1 MB)
  int*   n_items = items + 262144;

  // K0: fp32 -> fp16 conversions
  {
    int n1 = kB * kL * kD;
    int n2 = 3 * kD * kD;
    int n3 = kD * kD;
    cvt_f32_f16<<<(n1 / 8 + 255) / 256, 256, 0, stream>>>(x, x16, n1);
    cvt_f32_f16<<<(n2 / 8 + 255) / 256, 256, 0, stream>>>(in_proj_w, w16in, n2);
    cvt_f32_f16<<<(n3 / 8 + 255) / 256, 256, 0, stream>>>(out_proj_w, w16out, n3);
  }

  // K1: {q16, kv16} = x16 @ w16in^T  (M=16384, N=2304, K=768)
  hgemm_qkv<<<dim3(18, 128), 256, 0, stream>>>(x16, w16in, q16, kv16, kB * kL);

  // K2: u16[b,d,t] = conv_k * conv_v
  dwconv_mul<<<dim3(kL / 32, kD / 32, kB), dim3(32, 8), 0, stream>>>(
      kv16, sck_w, sck_b, scv_w, scv_b, u16);

  // zero y (kv16 dead after K2; y overlays it)
  hipMemsetAsync(y, 0, (size_t)kB * kD * kL * sizeof(float), stream);

  // K3: filter hfd[d][t]
  hyena_filter<<<dim3(kL / 32), 256, 0, stream>>>(
      mlp_w1, mlp_b1, mlp_w2, mlp_b2, mlp_w3, mlp_b3, log_decay, hfd);

  // K4a: compact wave-granular worklist
  build_worklist<<<1, 768, 0, stream>>>(log_decay, items, n_items);

  // K4b: y[b,d,t] += causal conv(u16, hfd); one wave per item, 8-tap window
  long_conv_wl<<<2048, 256, 0, stream>>>(u16, hfd, log_decay, items, n_items, y);

  // K5: g16[b,t,d] = silu(q16) * y
  gate_transpose<<<dim3(kL / 32, kD / 32, kB), dim3(32, 8), 0, stream>>>(q16, y, g16);

  // K6: out = g16 @ w16out^T  (M=16384, N=768, K=768)
  hgemm_f32out<<<dim3(6, 128), 256, 0, stream>>>(g16, w16out, out, kB * kL, kD);
}

// Round 11
// 360.976 us; speedup vs baseline: 1.1976x; 1.0172x over previous
//
#include <hip/hip_runtime.h>
#include <math.h>

namespace {

constexpr int kB  = 2;
constexpr int kL  = 8192;
constexpr int kD  = 768;

typedef _Float16 f16;
typedef __attribute__((ext_vector_type(4))) _Float16 f16x4;
typedef __attribute__((ext_vector_type(8))) _Float16 f16x8;
typedef __attribute__((ext_vector_type(4))) float f32x4;

__device__ __forceinline__ void gload_lds16(const f16* g, f16* l) {
  __builtin_amdgcn_global_load_lds(
      (__attribute__((address_space(1))) void*)(g),
      (__attribute__((address_space(3))) void*)(l), 16, 0, 0);
}

// ---------------- K0: fp32 -> fp16 conversion ----------------
__global__ __launch_bounds__(256) void cvt_f32_f16(
    const float* __restrict__ s, f16* __restrict__ d, int n) {
  int t = blockIdx.x * 256 + threadIdx.x;
  int i = t * 8;
  if (i >= n) return;
  float4 a = *(const float4*)(s + i);
  float4 b = *(const float4*)(s + i + 4);
  f16x8 v;
  v[0] = (f16)a.x; v[1] = (f16)a.y; v[2] = (f16)a.z; v[3] = (f16)a.w;
  v[4] = (f16)b.x; v[5] = (f16)b.y; v[6] = (f16)b.z; v[7] = (f16)b.w;
  *(f16x8*)(d + i) = v;
}

// ================= GEMM core (BK=64, XOR-swizzled LDS, XCD swizzle) =========
// Staging: pass i (0..3), row = i*32 + (tid>>3); source col-chunk is
// XOR-swizzled (cg = (tid&7)^((tid>>3)&7)) so linear global_load_lds dest +
// swizzled ds_read are consistent (both-sides-or-neither rule).
// Read: chunk = (kk*4+fq) ^ (fr&7)  -> 8 lanes per 16B chunk = 2/bank (free).

// ---------------- K1: qkv projection (fp16 MFMA), split outputs ----------------
__global__ __launch_bounds__(256) void hgemm_qkv(
    const f16* __restrict__ A, const f16* __restrict__ W,
    f16* __restrict__ q16, f16* __restrict__ kv16, int M) {
  constexpr int K = 768;
  __shared__ f16 As[128 * 64];
  __shared__ f16 Bs[128 * 64];
  const int tid = threadIdx.x;
  // XCD-aware bijective swizzle (nwg = 18*128 = 2304, divisible by 8)
  const int nwg = gridDim.x * gridDim.y;
  const int lin = blockIdx.y * gridDim.x + blockIdx.x;
  const int wg  = (lin & 7) * (nwg >> 3) + (lin >> 3);
  const int bm = wg / gridDim.x;
  const int bn = wg % gridDim.x;
  const int lane = tid & 63;
  const int wv = tid >> 6;
  const int wr = wv >> 1, wc = wv & 1;
  const int fr = lane & 15, fq = lane >> 4;
  const int srow = tid >> 3;                       // 0..31
  const int scg  = ((tid & 7) ^ ((tid >> 3) & 7)) * 8;  // swizzled source col
  const int rsw  = fr & 7;                         // read-side XOR key
  const f16* Ab = A + (size_t)bm * 128 * K;
  const f16* Wb = W + (size_t)bn * 128 * K;
  f32x4 acc[4][4];
#pragma unroll
  for (int m = 0; m < 4; ++m)
#pragma unroll
    for (int n = 0; n < 4; ++n)
#pragma unroll
      for (int j = 0; j < 4; ++j) acc[m][n][j] = 0.f;

  for (int k0 = 0; k0 < K; k0 += 64) {
#pragma unroll
    for (int i = 0; i < 4; ++i) {
      gload_lds16(Ab + (size_t)(i * 32 + srow) * K + k0 + scg, As + i * 2048 + wv * 512);
      gload_lds16(Wb + (size_t)(i * 32 + srow) * K + k0 + scg, Bs + i * 2048 + wv * 512);
    }
    __syncthreads();
#pragma unroll
    for (int kk = 0; kk < 2; ++kk) {
      f16x8 af[4], bf[4];
#pragma unroll
      for (int m = 0; m < 4; ++m)
        af[m] = *(const f16x8*)&As[(wr * 64 + m * 16 + fr) * 64 + (((kk * 4 + fq) ^ rsw) << 3)];
#pragma unroll
      for (int n = 0; n < 4; ++n)
        bf[n] = *(const f16x8*)&Bs[(wc * 64 + n * 16 + fr) * 64 + (((kk * 4 + fq) ^ rsw) << 3)];
#pragma unroll
      for (int m = 0; m < 4; ++m)
#pragma unroll
        for (int n = 0; n < 4; ++n)
          acc[m][n] = __builtin_amdgcn_mfma_f32_16x16x32_f16(af[m], bf[n], acc[m][n], 0, 0, 0);
    }
    __syncthreads();
  }
#pragma unroll
  for (int m = 0; m < 4; ++m) {
    int grow = bm * 128 + wr * 64 + m * 16 + fq * 4;
#pragma unroll
    for (int n = 0; n < 4; ++n) {
      int gcol = bn * 128 + wc * 64 + n * 16 + fr;
      f16* dst;
      int ldc, col;
      if (gcol < 768) { dst = q16; ldc = 768; col = gcol; }
      else            { dst = kv16; ldc = 1536; col = gcol - 768; }
#pragma unroll
      for (int j = 0; j < 4; ++j)
        dst[(size_t)(grow + j) * ldc + col] = (f16)acc[m][n][j];
    }
  }
}

// ---------------- K6: out = g16 @ w16out^T (fp16 MFMA, fp32 out) ----------------
__global__ __launch_bounds__(256) void hgemm_f32out(
    const f16* __restrict__ A, const f16* __restrict__ W,
    float* __restrict__ C, int M, int N) {
  constexpr int K = 768;
  __shared__ f16 As[128 * 64];
  __shared__ f16 Bs[128 * 64];
  const int tid = threadIdx.x;
  const int nwg = gridDim.x * gridDim.y;  // 6*128 = 768, divisible by 8
  const int lin = blockIdx.y * gridDim.x + blockIdx.x;
  const int wg  = (lin & 7) * (nwg >> 3) + (lin >> 3);
  const int bm = wg / gridDim.x;
  const int bn = wg % gridDim.x;
  const int lane = tid & 63;
  const int wv = tid >> 6;
  const int wr = wv >> 1, wc = wv & 1;
  const int fr = lane & 15, fq = lane >> 4;
  const int srow = tid >> 3;
  const int scg  = ((tid & 7) ^ ((tid >> 3) & 7)) * 8;
  const int rsw  = fr & 7;
  const f16* Ab = A + (size_t)bm * 128 * K;
  const f16* Wb = W + (size_t)bn * 128 * K;
  f32x4 acc[4][4];
#pragma unroll
  for (int m = 0; m < 4; ++m)
#pragma unroll
    for (int n = 0; n < 4; ++n)
#pragma unroll
      for (int j = 0; j < 4; ++j) acc[m][n][j] = 0.f;

  for (int k0 = 0; k0 < K; k0 += 64) {
#pragma unroll
    for (int i = 0; i < 4; ++i) {
      gload_lds16(Ab + (size_t)(i * 32 + srow) * K + k0 + scg, As + i * 2048 + wv * 512);
      gload_lds16(Wb + (size_t)(i * 32 + srow) * K + k0 + scg, Bs + i * 2048 + wv * 512);
    }
    __syncthreads();
#pragma unroll
    for (int kk = 0; kk < 2; ++kk) {
      f16x8 af[4], bf[4];
#pragma unroll
      for (int m = 0; m < 4; ++m)
        af[m] = *(const f16x8*)&As[(wr * 64 + m * 16 + fr) * 64 + (((kk * 4 + fq) ^ rsw) << 3)];
#pragma unroll
      for (int n = 0; n < 4; ++n)
        bf[n] = *(const f16x8*)&Bs[(wc * 64 + n * 16 + fr) * 64 + (((kk * 4 + fq) ^ rsw) << 3)];
#pragma unroll
      for (int m = 0; m < 4; ++m)
#pragma unroll
        for (int n = 0; n < 4; ++n)
          acc[m][n] = __builtin_amdgcn_mfma_f32_16x16x32_f16(af[m], bf[n], acc[m][n], 0, 0, 0);
    }
    __syncthreads();
  }
#pragma unroll
  for (int m = 0; m < 4; ++m) {
    int grow = bm * 128 + wr * 64 + m * 16 + fq * 4;
#pragma unroll
    for (int n = 0; n < 4; ++n) {
      int gcol = bn * 128 + wc * 64 + n * 16 + fr;
#pragma unroll
      for (int j = 0; j < 4; ++j)
        C[(size_t)(grow + j) * N + gcol] = acc[m][n][j];
    }
  }
}

// ---------------- K2: depthwise causal conv(k=3) on k,v + product, transpose ----------------
__global__ __launch_bounds__(256) void dwconv_mul(
    const f16* __restrict__ kv,
    const float* __restrict__ sck_w, const float* __restrict__ sck_b,
    const float* __restrict__ scv_w, const float* __restrict__ scv_b,
    f16* __restrict__ u) {
  __shared__ float ks[34][33];
  __shared__ float vs[34][33];
  const int b  = blockIdx.z;
  const int d0 = blockIdx.y * 32;
  const int t0 = blockIdx.x * 32;
  const int tx = threadIdx.x;
  const int ty = threadIdx.y;
  const f16* base = kv + (size_t)b * kL * (2 * kD);
  for (int r = ty; r < 34; r += 8) {
    int t = t0 - 2 + r;
    float kk = 0.f, vv = 0.f;
    if (t >= 0) {
      kk = (float)base[(size_t)t * (2 * kD) + d0 + tx];
      vv = (float)base[(size_t)t * (2 * kD) + kD + d0 + tx];
    }
    ks[r][tx] = kk;
    vs[r][tx] = vv;
  }
  __syncthreads();
#pragma unroll
  for (int i = 0; i < 4; ++i) {
    int dd = ty + 8 * i;
    int d = d0 + dd;
    float kw0 = sck_w[d * 3 + 0], kw1 = sck_w[d * 3 + 1], kw2 = sck_w[d * 3 + 2];
    float vw0 = scv_w[d * 3 + 0], vw1 = scv_w[d * 3 + 1], vw2 = scv_w[d * 3 + 2];
    float kc = kw0 * ks[tx][dd] + kw1 * ks[tx + 1][dd] + kw2 * ks[tx + 2][dd] + sck_b[d];
    float vc = vw0 * vs[tx][dd] + vw1 * vs[tx + 1][dd] + vw2 * vs[tx + 2][dd] + scv_b[d];
    u[((size_t)b * kD + d) * kL + t0 + tx] = (f16)(kc * vc);
  }
}

// ---------------- K3: hyena filter  hfd[d][t] (fp32) ----------------
__global__ __launch_bounds__(256) void hyena_filter(
    const float* __restrict__ w1, const float* __restrict__ b1,
    const float* __restrict__ w2, const float* __restrict__ b2,
    const float* __restrict__ w3, const float* __restrict__ b3,
    const float* __restrict__ log_decay, float* __restrict__ hfd) {
  __shared__ float w1s[64 * 65];
  __shared__ float w2s[64 * 65];
  __shared__ float h2s[32][64];
  __shared__ float pe[64];
  __shared__ float h1v[64];
  const int tid = threadIdx.x;
  for (int i = tid; i < 64 * 64; i += 256) {
    w1s[(i >> 6) * 65 + (i & 63)] = w1[i];
    w2s[(i >> 6) * 65 + (i & 63)] = w2[i];
  }
  __syncthreads();
  const int tbase = blockIdx.x * 32;
  const float TWO_PI = 6.28318530717958647692f;
  for (int tt = 0; tt < 32; ++tt) {
    int t = tbase + tt;
    float tn = (float)t / 8191.0f;
    if (tid < 64) {
      float f = TWO_PI * (float)((tid & 31) + 1);
      pe[tid] = (tid < 32) ? sinf(tn * f) : cosf(tn * f);
    }
    __syncthreads();
    if (tid < 64) {
      float s = b1[tid];
      for (int j = 0; j < 64; ++j) s += pe[j] * w1s[tid * 65 + j];
      h1v[tid] = s / (1.0f + expf(-s));
    }
    __syncthreads();
    if (tid < 64) {
      float s = b2[tid];
      for (int j = 0; j < 64; ++j) s += h1v[j] * w2s[tid * 65 + j];
      h2s[tt][tid] = s / (1.0f + expf(-s));
    }
    __syncthreads();
  }
  for (int d = tid; d < kD; d += 256) {
    float a = fabsf(log_decay[d]);
    float bb = b3[d];
    float acc[32];
#pragma unroll
    for (int tt = 0; tt < 32; ++tt) acc[tt] = bb;
    for (int j = 0; j < 64; ++j) {
      float w = w3[d * 64 + j];
#pragma unroll
      for (int tt = 0; tt < 32; ++tt) acc[tt] += h2s[tt][j] * w;
    }
    for (int tt = 0; tt < 32; ++tt) {
      int t = tbase + tt;
      hfd[(size_t)d * kL + t] = acc[tt] * expf(-a * (float)t);
    }
  }
}

// ---------------- truncation length (shared by K4a/K4b; MUST match) ----------------
__device__ __forceinline__ int trunc_len(float a) {
  int Td = (a * (float)kL <= 16.0f) ? kL : ((int)(16.0f / a) + 1);
  Td = (Td + 7) & ~7;            // multiple of 8 -> s_end always multiple of 8
  return min(Td, kL);
}

// ---------------- K4a: build compact worklist (wave-granular items) ----------------
// item = d | tc<<10 | sc<<15 ; t-chunk = 256 outputs, s-chunk = 256 taps.
__global__ __launch_bounds__(768) void build_worklist(
    const float* __restrict__ log_decay, int* __restrict__ items,
    int* __restrict__ n_items) {
  __shared__ int cnt[768];
  const int d = threadIdx.x;
  float a = fabsf(log_decay[d]);
  int Td = trunc_len(a);
  int c = 0;
#pragma unroll
  for (int tc = 0; tc < 32; ++tc) {
    int smax = min(Td, (tc + 1) * 256);
    c += (smax + 255) >> 8;
  }
  cnt[d] = c;
  __syncthreads();
  for (int off = 1; off < 768; off <<= 1) {
    int v = (d >= off) ? cnt[d - off] : 0;
    __syncthreads();
    cnt[d] += v;
    __syncthreads();
  }
  int base = cnt[d] - c;  // exclusive prefix
  for (int tc = 0; tc < 32; ++tc) {
    int smax = min(Td, (tc + 1) * 256);
    int nsc = (smax + 255) >> 8;
    for (int sc = 0; sc < nsc; ++sc)
      items[base++] = d | (tc << 10) | (sc << 15);
  }
  if (d == 767) n_items[0] = cnt[767];
}

// ---------------- K4b: causal long conv, one WAVE per item ----------------
constexpr int TC = 256;
__device__ __forceinline__ f16x4 ld4(const f16* p, int off) {
  return *(const f16x4*)(p + off);
}
__device__ __forceinline__ f16x4 ld4z(const f16* p, int off) {
  f16x4 v = *(const f16x4*)(p + off);
  if (off < 0) v = (f16x4){};
  return v;
}
#define TAPS8(acc, Aq, Bq, Cq)                                                                                       \
  acc.x += h4a.x * (float)Aq[0]; acc.y += h4a.x * (float)Aq[1]; acc.z += h4a.x * (float)Aq[2]; acc.w += h4a.x * (float)Aq[3]; \
  acc.x += h4a.y * (float)Bq[3]; acc.y += h4a.y * (float)Aq[0]; acc.z += h4a.y * (float)Aq[1]; acc.w += h4a.y * (float)Aq[2]; \
  acc.x += h4a.z * (float)Bq[2]; acc.y += h4a.z * (float)Bq[3]; acc.z += h4a.z * (float)Aq[0]; acc.w += h4a.z * (float)Aq[1]; \
  acc.x += h4a.w * (float)Bq[1]; acc.y += h4a.w * (float)Bq[2]; acc.z += h4a.w * (float)Bq[3]; acc.w += h4a.w * (float)Aq[0]; \
  acc.x += h4b.x * (float)Bq[0]; acc.y += h4b.x * (float)Bq[1]; acc.z += h4b.x * (float)Bq[2]; acc.w += h4b.x * (float)Bq[3]; \
  acc.x += h4b.y * (float)Cq[3]; acc.y += h4b.y * (float)Bq[0]; acc.z += h4b.y * (float)Bq[1]; acc.w += h4b.y * (float)Bq[2]; \
  acc.x += h4b.z * (float)Cq[2]; acc.y += h4b.z * (float)Cq[3]; acc.z += h4b.z * (float)Bq[0]; acc.w += h4b.z * (float)Bq[1]; \
  acc.x += h4b.w * (float)Cq[1]; acc.y += h4b.w * (float)Cq[2]; acc.z += h4b.w * (float)Cq[3]; acc.w += h4b.w * (float)Bq[0];
__global__ __launch_bounds__(256) void long_conv_wl(
    const f16* __restrict__ u, const float* __restrict__ hfd,
    const float* __restrict__ log_decay,
    const int* __restrict__ items, const int* __restrict__ n_items,
    float* __restrict__ y) {
  const int lane = threadIdx.x & 63;
  const int wid  = threadIdx.x >> 6;
  const int n = __builtin_amdgcn_readfirstlane(n_items[0]);
  for (int it = blockIdx.x * 4 + wid; it < n; it += gridDim.x * 4) {
    const int item = __builtin_amdgcn_readfirstlane(items[it]);
    const int d  = item & 1023;
    const int tc = (item >> 10) & 31;
    const int sc = item >> 15;
    const float a = fabsf(log_decay[d]);
    const int Td = trunc_len(a);
    const int t0 = tc << 8;
    const int smax = min(Td, t0 + TC);
    const int s_begin = sc << 8;
    const int s_end = min(s_begin + TC, smax);
    const f16* ub0 = u + (size_t)d * kL;           // b=0
    const f16* ub1 = u + (size_t)(kD + d) * kL;    // b=1
    const float* hb = hfd + (size_t)d * kL;
    const int T = t0 + 4 * lane;
    float4 acc0 = make_float4(0.f, 0.f, 0.f, 0.f);
    float4 acc1 = make_float4(0.f, 0.f, 0.f, 0.f);
    int base = T - s_begin;            // >= 0 (s_begin <= t0 <= T), mult of 4
    f16x4 A0 = ld4(ub0, base),      A1 = ld4(ub1, base);
    f16x4 B0 = ld4z(ub0, base - 4), B1 = ld4z(ub1, base - 4);
    f16x4 C0 = ld4z(ub0, base - 8), C1 = ld4z(ub1, base - 8);
    float4 h4a = *(const float4*)(hb + s_begin);       // wave-uniform
    float4 h4b = *(const float4*)(hb + s_begin + 4);
    for (int ss = s_begin; ss < s_end; ss += 8) {
      const int nb = base - 8;
      f16x4 nB0 = ld4z(ub0, nb - 4), nB1 = ld4z(ub1, nb - 4);
      f16x4 nC0 = ld4z(ub0, nb - 8), nC1 = ld4z(ub1, nb - 8);
      float4 nha = *(const float4*)(hb + ss + 8);
      float4 nhb = *(const float4*)(hb + ss + 12);
      TAPS8(acc0, A0, B0, C0);
      TAPS8(acc1, A1, B1, C1);
      A0 = C0; B0 = nB0; C0 = nC0;
      A1 = C1; B1 = nB1; C1 = nC1;
      h4a = nha; h4b = nhb;
      base = nb;
    }
    float* y0 = &y[(size_t)d * kL + t0 + 4 * lane];
    float* y1 = &y[(size_t)(kD + d) * kL + t0 + 4 * lane];
    if (smax <= TC) {  // sole writer for this (d, t-chunk)
      *(float4*)y0 = acc0;
      *(float4*)y1 = acc1;
    } else {
      atomicAdd(y0 + 0, acc0.x); atomicAdd(y0 + 1, acc0.y);
      atomicAdd(y0 + 2, acc0.z); atomicAdd(y0 + 3, acc0.w);
      atomicAdd(y1 + 0, acc1.x); atomicAdd(y1 + 1, acc1.y);
      atomicAdd(y1 + 2, acc1.z); atomicAdd(y1 + 3, acc1.w);
    }
  }
}

// ---------------- K5: gate + transpose  g16[b,t,d] = silu(q16[b,t,d]) * y[b,d,t] ----------------
__global__ __launch_bounds__(256) void gate_transpose(
    const f16* __restrict__ q, const float* __restrict__ y,
    f16* __restrict__ g) {
  __shared__ float ys[32][33];
  const int b  = blockIdx.z;
  const int t0 = blockIdx.x * 32;
  const int d0 = blockIdx.y * 32;
  const int tx = threadIdx.x;
  const int ty = threadIdx.y;
#pragma unroll
  for (int i = 0; i < 4; ++i) {
    int dd = ty + 8 * i;
    ys[dd][tx] = y[((size_t)b * kD + d0 + dd) * kL + t0 + tx];
  }
  __syncthreads();
  const f16* qb = q + (size_t)b * kL * kD;
#pragma unroll
  for (int i = 0; i < 4; ++i) {
    int t = t0 + ty + 8 * i;
    int d = d0 + tx;
    float qv = (float)qb[(size_t)t * kD + d];
    float sq = qv / (1.0f + expf(-qv));
    g[((size_t)b * kL + t) * kD + d] = (f16)(sq * ys[tx][ty + 8 * i]);
  }
}

}  // namespace

extern "C" void kernel_launch(void* const* d_in, const int* in_sizes, int n_in,
                              void* d_out, int out_size, void* d_ws, size_t ws_size,
                              hipStream_t stream) {
  const float* x          = (const float*)d_in[0];
  const float* in_proj_w  = (const float*)d_in[1];
  const float* sck_w      = (const float*)d_in[2];
  const float* sck_b      = (const float*)d_in[3];
  const float* scv_w      = (const float*)d_in[4];
  const float* scv_b      = (const float*)d_in[5];
  const float* mlp_w1     = (const float*)d_in[6];
  const float* mlp_b1     = (const float*)d_in[7];
  const float* mlp_w2     = (const float*)d_in[8];
  const float* mlp_b2     = (const float*)d_in[9];
  const float* mlp_w3     = (const float*)d_in[10];
  const float* mlp_b3     = (const float*)d_in[11];
  const float* log_decay  = (const float*)d_in[12];
  const float* out_proj_w = (const float*)d_in[13];
  float* out = (float*)d_out;

  // workspace layout (bytes), ~158 MB total
  char* base = (char*)d_ws;
  const size_t S1 = 25165824;   // q16  [B][L][D] fp16
  const size_t S2 = 50331648;   // kv16 [B][L][2D] fp16  -> later y [B][D][L] fp32
  const size_t S3 = 25165824;   // u16  [B][D][L] fp16
  const size_t S4 = 25165824;   // x16  [B][L][D] fp16   -> later g16
  const size_t S5 = 25165824;   // hfd  [D][L] fp32
  f16*   q16   = (f16*)base;
  f16*   kv16  = (f16*)(base + S1);
  float* y     = (float*)(base + S1);
  f16*   u16   = (f16*)(base + S1 + S2);
  f16*   x16   = (f16*)(base + S1 + S2 + S3);
  f16*   g16   = x16;
  float* hfd   = (float*)(base + S1 + S2 + S3 + S4);
  f16*   w16in = (f16*)(base + S1 + S2 + S3 + S4 + S5);
  f16*   w16out= w16in + (size_t)3 * kD * kD;
  int*   items = (int*)(w16out + (size_t)kD * kD);   // 256K ints (1 MB)
  int*   n_items = items + 262144;

  // K0: fp32 -> fp16 conversions
  {
    int n1 = kB * kL * kD;
    int n2 = 3 * kD * kD;
    int n3 = kD * kD;
    cvt_f32_f16<<<(n1 / 8 + 255) / 256, 256, 0, stream>>>(x, x16, n1);
    cvt_f32_f16<<<(n2 / 8 + 255) / 256, 256, 0, stream>>>(in_proj_w, w16in, n2);
    cvt_f32_f16<<<(n3 / 8 + 255) / 256, 256, 0, stream>>>(out_proj_w, w16out, n3);
  }

  // K1: {q16, kv16} = x16 @ w16in^T  (M=16384, N=2304, K=768)
  hgemm_qkv<<<dim3(18, 128), 256, 0, stream>>>(x16, w16in, q16, kv16, kB * kL);

  // K2: u16[b,d,t] = conv_k * conv_v
  dwconv_mul<<<dim3(kL / 32, kD / 32, kB), dim3(32, 8), 0, stream>>>(
      kv16, sck_w, sck_b, scv_w, scv_b, u16);

  // zero y (kv16 dead after K2; y overlays it)
  hipMemsetAsync(y, 0, (size_t)kB * kD * kL * sizeof(float), stream);

  // K3: filter hfd[d][t]
  hyena_filter<<<dim3(kL / 32), 256, 0, stream>>>(
      mlp_w1, mlp_b1, mlp_w2, mlp_b2, mlp_w3, mlp_b3, log_decay, hfd);

  // K4a: compact wave-granular worklist
  build_worklist<<<1, 768, 0, stream>>>(log_decay, items, n_items);

  // K4b: y[b,d,t] += causal conv(u16, hfd); one wave per item, 8-tap window
  long_conv_wl<<<2048, 256, 0, stream>>>(u16, hfd, log_decay, items, n_items, y);

  // K5: g16[b,t,d] = silu(q16) * y
  gate_transpose<<<dim3(kL / 32, kD / 32, kB), dim3(32, 8), 0, stream>>>(q16, y, g16);

  // K6: out = g16 @ w16out^T  (M=16384, N=768, K=768)
  hgemm_f32out<<<dim3(6, 128), 256, 0, stream>>>(g16, w16out, out, kB * kL, kD);
}

// Round 12
// 330.441 us; speedup vs baseline: 1.3083x; 1.0924x over previous
//
#include <hip/hip_runtime.h>
#include <math.h>

namespace {

constexpr int kB  = 2;
constexpr int kL  = 8192;
constexpr int kD  = 768;
constexpr int HR  = 8240;  // hp16 row stride (f16): [32 zeros][8192 h][16 zero pad]
constexpr int UR  = 8200;  // ur row stride (f16): ur[8192 - t] = u[t]

typedef _Float16 f16;
typedef __attribute__((ext_vector_type(4))) _Float16 f16x4;
typedef __attribute__((ext_vector_type(8))) _Float16 f16x8;
typedef __attribute__((ext_vector_type(4))) float f32x4;

__device__ __forceinline__ void gload_lds16(const f16* g, f16* l) {
  __builtin_amdgcn_global_load_lds(
      (__attribute__((address_space(1))) void*)(g),
      (__attribute__((address_space(3))) void*)(l), 16, 0, 0);
}

// ---------------- K0: fp32 -> fp16 conversion ----------------
__global__ __launch_bounds__(256) void cvt_f32_f16(
    const float* __restrict__ s, f16* __restrict__ d, int n) {
  int t = blockIdx.x * 256 + threadIdx.x;
  int i = t * 8;
  if (i >= n) return;
  float4 a = *(const float4*)(s + i);
  float4 b = *(const float4*)(s + i + 4);
  f16x8 v;
  v[0] = (f16)a.x; v[1] = (f16)a.y; v[2] = (f16)a.z; v[3] = (f16)a.w;
  v[4] = (f16)b.x; v[5] = (f16)b.y; v[6] = (f16)b.z; v[7] = (f16)b.w;
  *(f16x8*)(d + i) = v;
}

// ---------------- K1: qkv projection (fp16 MFMA), split outputs ----------------
__global__ __launch_bounds__(256) void hgemm_qkv(
    const f16* __restrict__ A, const f16* __restrict__ W,
    f16* __restrict__ q16, f16* __restrict__ kv16, int M) {
  constexpr int K = 768;
  __shared__ f16 As[128 * 64];
  __shared__ f16 Bs[128 * 64];
  const int tid = threadIdx.x;
  const int nwg = gridDim.x * gridDim.y;
  const int lin = blockIdx.y * gridDim.x + blockIdx.x;
  const int wg  = (lin & 7) * (nwg >> 3) + (lin >> 3);
  const int bm = wg / gridDim.x;
  const int bn = wg % gridDim.x;
  const int lane = tid & 63;
  const int wv = tid >> 6;
  const int wr = wv >> 1, wc = wv & 1;
  const int fr = lane & 15, fq = lane >> 4;
  const int srow = tid >> 3;
  const int scg  = ((tid & 7) ^ ((tid >> 3) & 7)) * 8;
  const int rsw  = fr & 7;
  const f16* Ab = A + (size_t)bm * 128 * K;
  const f16* Wb = W + (size_t)bn * 128 * K;
  f32x4 acc[4][4];
#pragma unroll
  for (int m = 0; m < 4; ++m)
#pragma unroll
    for (int n = 0; n < 4; ++n)
#pragma unroll
      for (int j = 0; j < 4; ++j) acc[m][n][j] = 0.f;

  for (int k0 = 0; k0 < K; k0 += 64) {
#pragma unroll
    for (int i = 0; i < 4; ++i) {
      gload_lds16(Ab + (size_t)(i * 32 + srow) * K + k0 + scg, As + i * 2048 + wv * 512);
      gload_lds16(Wb + (size_t)(i * 32 + srow) * K + k0 + scg, Bs + i * 2048 + wv * 512);
    }
    __syncthreads();
#pragma unroll
    for (int kk = 0; kk < 2; ++kk) {
      f16x8 af[4], bf[4];
#pragma unroll
      for (int m = 0; m < 4; ++m)
        af[m] = *(const f16x8*)&As[(wr * 64 + m * 16 + fr) * 64 + (((kk * 4 + fq) ^ rsw) << 3)];
#pragma unroll
      for (int n = 0; n < 4; ++n)
        bf[n] = *(const f16x8*)&Bs[(wc * 64 + n * 16 + fr) * 64 + (((kk * 4 + fq) ^ rsw) << 3)];
#pragma unroll
      for (int m = 0; m < 4; ++m)
#pragma unroll
        for (int n = 0; n < 4; ++n)
          acc[m][n] = __builtin_amdgcn_mfma_f32_16x16x32_f16(af[m], bf[n], acc[m][n], 0, 0, 0);
    }
    __syncthreads();
  }
#pragma unroll
  for (int m = 0; m < 4; ++m) {
    int grow = bm * 128 + wr * 64 + m * 16 + fq * 4;
#pragma unroll
    for (int n = 0; n < 4; ++n) {
      int gcol = bn * 128 + wc * 64 + n * 16 + fr;
      f16* dst;
      int ldc, col;
      if (gcol < 768) { dst = q16; ldc = 768; col = gcol; }
      else            { dst = kv16; ldc = 1536; col = gcol - 768; }
#pragma unroll
      for (int j = 0; j < 4; ++j)
        dst[(size_t)(grow + j) * ldc + col] = (f16)acc[m][n][j];
    }
  }
}

// ---------------- K6: out = g16 @ w16out^T (fp16 MFMA, fp32 out) ----------------
__global__ __launch_bounds__(256) void hgemm_f32out(
    const f16* __restrict__ A, const f16* __restrict__ W,
    float* __restrict__ C, int M, int N) {
  constexpr int K = 768;
  __shared__ f16 As[128 * 64];
  __shared__ f16 Bs[128 * 64];
  const int tid = threadIdx.x;
  const int nwg = gridDim.x * gridDim.y;
  const int lin = blockIdx.y * gridDim.x + blockIdx.x;
  const int wg  = (lin & 7) * (nwg >> 3) + (lin >> 3);
  const int bm = wg / gridDim.x;
  const int bn = wg % gridDim.x;
  const int lane = tid & 63;
  const int wv = tid >> 6;
  const int wr = wv >> 1, wc = wv & 1;
  const int fr = lane & 15, fq = lane >> 4;
  const int srow = tid >> 3;
  const int scg  = ((tid & 7) ^ ((tid >> 3) & 7)) * 8;
  const int rsw  = fr & 7;
  const f16* Ab = A + (size_t)bm * 128 * K;
  const f16* Wb = W + (size_t)bn * 128 * K;
  f32x4 acc[4][4];
#pragma unroll
  for (int m = 0; m < 4; ++m)
#pragma unroll
    for (int n = 0; n < 4; ++n)
#pragma unroll
      for (int j = 0; j < 4; ++j) acc[m][n][j] = 0.f;

  for (int k0 = 0; k0 < K; k0 += 64) {
#pragma unroll
    for (int i = 0; i < 4; ++i) {
      gload_lds16(Ab + (size_t)(i * 32 + srow) * K + k0 + scg, As + i * 2048 + wv * 512);
      gload_lds16(Wb + (size_t)(i * 32 + srow) * K + k0 + scg, Bs + i * 2048 + wv * 512);
    }
    __syncthreads();
#pragma unroll
    for (int kk = 0; kk < 2; ++kk) {
      f16x8 af[4], bf[4];
#pragma unroll
      for (int m = 0; m < 4; ++m)
        af[m] = *(const f16x8*)&As[(wr * 64 + m * 16 + fr) * 64 + (((kk * 4 + fq) ^ rsw) << 3)];
#pragma unroll
      for (int n = 0; n < 4; ++n)
        bf[n] = *(const f16x8*)&Bs[(wc * 64 + n * 16 + fr) * 64 + (((kk * 4 + fq) ^ rsw) << 3)];
#pragma unroll
      for (int m = 0; m < 4; ++m)
#pragma unroll
        for (int n = 0; n < 4; ++n)
          acc[m][n] = __builtin_amdgcn_mfma_f32_16x16x32_f16(af[m], bf[n], acc[m][n], 0, 0, 0);
    }
    __syncthreads();
  }
#pragma unroll
  for (int m = 0; m < 4; ++m) {
    int grow = bm * 128 + wr * 64 + m * 16 + fq * 4;
#pragma unroll
    for (int n = 0; n < 4; ++n) {
      int gcol = bn * 128 + wc * 64 + n * 16 + fr;
#pragma unroll
      for (int j = 0; j < 4; ++j)
        C[(size_t)(grow + j) * N + gcol] = acc[m][n][j];
    }
  }
}

// ---------------- K2: depthwise causal conv(k=3) + product, transpose+reverse ----------------
// out: ur[b,d, 8192 - t] = conv_k(t) * conv_v(t)
__global__ __launch_bounds__(256) void dwconv_mul(
    const f16* __restrict__ kv,
    const float* __restrict__ sck_w, const float* __restrict__ sck_b,
    const float* __restrict__ scv_w, const float* __restrict__ scv_b,
    f16* __restrict__ ur) {
  __shared__ float ks[34][33];
  __shared__ float vs[34][33];
  const int b  = blockIdx.z;
  const int d0 = blockIdx.y * 32;
  const int t0 = blockIdx.x * 32;
  const int tx = threadIdx.x;
  const int ty = threadIdx.y;
  const f16* base = kv + (size_t)b * kL * (2 * kD);
  for (int r = ty; r < 34; r += 8) {
    int t = t0 - 2 + r;
    float kk = 0.f, vv = 0.f;
    if (t >= 0) {
      kk = (float)base[(size_t)t * (2 * kD) + d0 + tx];
      vv = (float)base[(size_t)t * (2 * kD) + kD + d0 + tx];
    }
    ks[r][tx] = kk;
    vs[r][tx] = vv;
  }
  __syncthreads();
#pragma unroll
  for (int i = 0; i < 4; ++i) {
    int dd = ty + 8 * i;
    int d = d0 + dd;
    float kw0 = sck_w[d * 3 + 0], kw1 = sck_w[d * 3 + 1], kw2 = sck_w[d * 3 + 2];
    float vw0 = scv_w[d * 3 + 0], vw1 = scv_w[d * 3 + 1], vw2 = scv_w[d * 3 + 2];
    float kc = kw0 * ks[tx][dd] + kw1 * ks[tx + 1][dd] + kw2 * ks[tx + 2][dd] + sck_b[d];
    float vc = vw0 * vs[tx][dd] + vw1 * vs[tx + 1][dd] + vw2 * vs[tx + 2][dd] + scv_b[d];
    ur[((size_t)b * kD + d) * UR + (kL - (t0 + tx))] = (f16)(kc * vc);
  }
}

// ---------------- K3: hyena filter -> hp16[d][32 + t] (f16, padded rows) ----------------
__global__ __launch_bounds__(256) void hyena_filter(
    const float* __restrict__ w1, const float* __restrict__ b1,
    const float* __restrict__ w2, const float* __restrict__ b2,
    const float* __restrict__ w3, const float* __restrict__ b3,
    const float* __restrict__ log_decay, f16* __restrict__ hp16) {
  __shared__ float w1s[64 * 65];
  __shared__ float w2s[64 * 65];
  __shared__ float h2s[32][64];
  __shared__ float pe[64];
  __shared__ float h1v[64];
  const int tid = threadIdx.x;
  for (int i = tid; i < 64 * 64; i += 256) {
    w1s[(i >> 6) * 65 + (i & 63)] = w1[i];
    w2s[(i >> 6) * 65 + (i & 63)] = w2[i];
  }
  __syncthreads();
  const int tbase = blockIdx.x * 32;
  const float TWO_PI = 6.28318530717958647692f;
  for (int tt = 0; tt < 32; ++tt) {
    int t = tbase + tt;
    float tn = (float)t / 8191.0f;
    if (tid < 64) {
      float f = TWO_PI * (float)((tid & 31) + 1);
      pe[tid] = (tid < 32) ? sinf(tn * f) : cosf(tn * f);
    }
    __syncthreads();
    if (tid < 64) {
      float s = b1[tid];
      for (int j = 0; j < 64; ++j) s += pe[j] * w1s[tid * 65 + j];
      h1v[tid] = s / (1.0f + expf(-s));
    }
    __syncthreads();
    if (tid < 64) {
      float s = b2[tid];
      for (int j = 0; j < 64; ++j) s += h1v[j] * w2s[tid * 65 + j];
      h2s[tt][tid] = s / (1.0f + expf(-s));
    }
    __syncthreads();
  }
  for (int d = tid; d < kD; d += 256) {
    float a = fabsf(log_decay[d]);
    float bb = b3[d];
    float acc[32];
#pragma unroll
    for (int tt = 0; tt < 32; ++tt) acc[tt] = bb;
    for (int j = 0; j < 64; ++j) {
      float w = w3[d * 64 + j];
#pragma unroll
      for (int tt = 0; tt < 32; ++tt) acc[tt] += h2s[tt][j] * w;
    }
    for (int tt = 0; tt < 32; ++tt) {
      int t = tbase + tt;
      hp16[(size_t)d * HR + 32 + t] = (f16)(acc[tt] * expf(-a * (float)t));
    }
  }
}

// ---------------- truncation length ----------------
__device__ __forceinline__ int trunc_len(float a) {
  int Td = (a * (float)kL <= 16.0f) ? kL : ((int)(16.0f / a) + 1);
  Td = (Td + 7) & ~7;
  return min(Td, kL);
}

// ---------------- K4: long conv via MFMA Toeplitz ----------------
// Wave = (d, 256-t tile). D[m][n] = y[T0 + m + 16n]:
//   A'[m][k] = hp[d][s0 + k + m]           (m=lane&15, k=8*(lane>>4)+e)
//   B'[n][k] = u[T0 + 16n - s0 - k + 32]   (n=lane&15) = ur[8192-X+e], X=T0+16n-s0-8fq+32
// hp head-padded with 32 zeros kills s<0 taps; B masked for u-idx outside [0,8191].
__device__ __forceinline__ void bmask(f16x8& v, int X) {
  if (X < 0 || X > kL) { v = (f16x8){}; return; }
  uint32_t* u = (uint32_t*)&v;
  if (X == 0)  { u[0] &= 0xFFFFu; u[1] = 0; u[2] = 0; u[3] = 0; }
  else if (X == kL) { u[0] &= 0xFFFF0000u; }
}
__global__ __launch_bounds__(256) void long_conv_mfma(
    const f16* __restrict__ ur, const f16* __restrict__ hp,
    const float* __restrict__ log_decay, float* __restrict__ y) {
  const int wid  = blockIdx.x * 4 + (threadIdx.x >> 6);  // 0..24575
  const int lane = threadIdx.x & 63;
  const int d  = wid >> 5;
  const int tc = wid & 31;
  const int T0 = tc << 8;
  const int fr = lane & 15, fq = lane >> 4;
  const float a = fabsf(log_decay[d]);
  const int S = min(trunc_len(a), T0 + 256);
  const int nck = (((S + 31) & ~31) >> 5) + 1;
  const f16* hrow = hp + (size_t)d * HR;
  const f16* u0 = ur + (size_t)d * UR;
  const f16* u1 = ur + (size_t)(kD + d) * UR;
  const int abase = 8 * fq + fr;
  const int xbase = T0 + 16 * fr - 8 * fq + 32;
  f32x4 acc0 = {0.f, 0.f, 0.f, 0.f};
  f32x4 acc1 = {0.f, 0.f, 0.f, 0.f};
  for (int c = 0; c < nck; ++c) {
    const int s0 = c << 5;
    const f16* hb = hrow + s0 + abase;
    f16x8 af;
#pragma unroll
    for (int e = 0; e < 8; ++e) af[e] = hb[e];
    const int X = xbase - s0;
    const int rb = kL - X;                    // multiple of 8
    f16x8 b0 = *(const f16x8*)(u0 + rb);
    f16x8 b1 = *(const f16x8*)(u1 + rb);
    bmask(b0, X);
    bmask(b1, X);
    acc0 = __builtin_amdgcn_mfma_f32_16x16x32_f16(af, b0, acc0, 0, 0, 0);
    acc1 = __builtin_amdgcn_mfma_f32_16x16x32_f16(af, b1, acc1, 0, 0, 0);
  }
  const size_t off = (size_t)T0 + 16 * fr + 4 * fq;
  *(f32x4*)&y[(size_t)d * kL + off] = acc0;
  *(f32x4*)&y[(size_t)(kD + d) * kL + off] = acc1;
}

// ---------------- K5: gate + transpose  g16[b,t,d] = silu(q16[b,t,d]) * y[b,d,t] ----------------
__global__ __launch_bounds__(256) void gate_transpose(
    const f16* __restrict__ q, const float* __restrict__ y,
    f16* __restrict__ g) {
  __shared__ float ys[32][33];
  const int b  = blockIdx.z;
  const int t0 = blockIdx.x * 32;
  const int d0 = blockIdx.y * 32;
  const int tx = threadIdx.x;
  const int ty = threadIdx.y;
#pragma unroll
  for (int i = 0; i < 4; ++i) {
    int dd = ty + 8 * i;
    ys[dd][tx] = y[((size_t)b * kD + d0 + dd) * kL + t0 + tx];
  }
  __syncthreads();
  const f16* qb = q + (size_t)b * kL * kD;
#pragma unroll
  for (int i = 0; i < 4; ++i) {
    int t = t0 + ty + 8 * i;
    int d = d0 + tx;
    float qv = (float)qb[(size_t)t * kD + d];
    float sq = qv / (1.0f + expf(-qv));
    g[((size_t)b * kL + t) * kD + d] = (f16)(sq * ys[tx][ty + 8 * i]);
  }
}

}  // namespace

extern "C" void kernel_launch(void* const* d_in, const int* in_sizes, int n_in,
                              void* d_out, int out_size, void* d_ws, size_t ws_size,
                              hipStream_t stream) {
  const float* x          = (const float*)d_in[0];
  const float* in_proj_w  = (const float*)d_in[1];
  const float* sck_w      = (const float*)d_in[2];
  const float* sck_b      = (const float*)d_in[3];
  const float* scv_w      = (const float*)d_in[4];
  const float* scv_b      = (const float*)d_in[5];
  const float* mlp_w1     = (const float*)d_in[6];
  const float* mlp_b1     = (const float*)d_in[7];
  const float* mlp_w2     = (const float*)d_in[8];
  const float* mlp_b2     = (const float*)d_in[9];
  const float* mlp_w3     = (const float*)d_in[10];
  const float* mlp_b3     = (const float*)d_in[11];
  const float* log_decay  = (const float*)d_in[12];
  const float* out_proj_w = (const float*)d_in[13];
  float* out = (float*)d_out;

  // workspace layout (bytes), ~143.3 MB total
  char* base = (char*)d_ws;
  const size_t S1  = 25165824;                      // q16  [B][L][D] fp16
  const size_t S2  = 50331648;                      // kv16 -> later y [B][D][L] fp32
  const size_t Sur = (size_t)kB * kD * UR * 2;      // ur   reversed u, 25,190,400
  const size_t S4  = 25165824;                      // x16 -> later g16
  const size_t Shp = (size_t)kD * HR * 2;           // hp16 padded filter, 12,656,640
  f16*   q16   = (f16*)base;
  f16*   kv16  = (f16*)(base + S1);
  float* y     = (float*)(base + S1);
  f16*   ur    = (f16*)(base + S1 + S2);
  f16*   x16   = (f16*)(base + S1 + S2 + Sur);
  f16*   g16   = x16;
  f16*   hp16  = (f16*)(base + S1 + S2 + Sur + S4);
  f16*   w16in = (f16*)(base + S1 + S2 + Sur + S4 + Shp);
  f16*   w16out= w16in + (size_t)3 * kD * kD;

  // K0: fp32 -> fp16 conversions
  {
    int n1 = kB * kL * kD;
    int n2 = 3 * kD * kD;
    int n3 = kD * kD;
    cvt_f32_f16<<<(n1 / 8 + 255) / 256, 256, 0, stream>>>(x, x16, n1);
    cvt_f32_f16<<<(n2 / 8 + 255) / 256, 256, 0, stream>>>(in_proj_w, w16in, n2);
    cvt_f32_f16<<<(n3 / 8 + 255) / 256, 256, 0, stream>>>(out_proj_w, w16out, n3);
  }

  // zero hp16 (head/tail pads must be 0; filter fills the middle)
  hipMemsetAsync(hp16, 0, Shp, stream);

  // K1: {q16, kv16} = x16 @ w16in^T  (M=16384, N=2304, K=768)
  hgemm_qkv<<<dim3(18, 128), 256, 0, stream>>>(x16, w16in, q16, kv16, kB * kL);

  // K2: ur[b,d,8192-t] = conv_k * conv_v
  dwconv_mul<<<dim3(kL / 32, kD / 32, kB), dim3(32, 8), 0, stream>>>(
      kv16, sck_w, sck_b, scv_w, scv_b, ur);

  // K3: filter hp16[d][32+t]
  hyena_filter<<<dim3(kL / 32), 256, 0, stream>>>(
      mlp_w1, mlp_b1, mlp_w2, mlp_b2, mlp_w3, mlp_b3, log_decay, hp16);

  // K4: y[b,d,t] = causal conv via MFMA Toeplitz; wave per (d, 256-t tile)
  long_conv_mfma<<<kD * 32 / 4, 256, 0, stream>>>(ur, hp16, log_decay, y);

  // K5: g16[b,t,d] = silu(q16) * y
  gate_transpose<<<dim3(kL / 32, kD / 32, kB), dim3(32, 8), 0, stream>>>(q16, y, g16);

  // K6: out = g16 @ w16out^T  (M=16384, N=768, K=768)
  hgemm_f32out<<<dim3(6, 128), 256, 0, stream>>>(g16, w16out, out, kB * kL, kD);
}